// Round 9
// baseline (1222.606 us; speedup 1.0000x reference)
//
#include <hip/hip_runtime.h>
#include <math.h>

typedef short  s16x8 __attribute__((ext_vector_type(8)));   // 8 bf16 bit-patterns (4 VGPRs)
typedef float  f32x4 __attribute__((ext_vector_type(4)));

static __device__ __forceinline__ float sigf(float x){ return 1.0f/(1.0f+__expf(-x)); }
static __device__ __forceinline__ float tanhf_fast(float x){
  float ax=fabsf(x); float e=__expf(-2.0f*ax); float t=(1.0f-e)/(1.0f+e); return copysignf(t,x);
}
static __device__ __forceinline__ unsigned short f2bf(float x){  // RNE f32->bf16 bits (host-side style, used in A-frag prep)
  unsigned int u = __float_as_uint(x);
  unsigned int r = (u + 0x7FFFu + ((u >> 16) & 1u)) >> 16;
  return (unsigned short)r;
}
static __device__ __forceinline__ float bf2f(unsigned short b){
  return __uint_as_float(((unsigned int)b) << 16);
}
// packed f32x2 -> bf16x2 (D.lo=cvt(S0), D.hi=cvt(S1)); rounding mode irrelevant:
// the lo term is computed from the ACTUAL hi bits, so the split self-corrects.
static __device__ __forceinline__ unsigned int cvt_pk_bf16(float a, float b){
  unsigned int r;
  asm("v_cvt_pk_bf16_f32 %0, %1, %2" : "=v"(r) : "v"(a), "v"(b));
  return r;
}
// quad/octet reduce helpers (verified r4) — used by L2/L3
static __device__ __forceinline__ float qsum(float v){
  v += __int_as_float(__builtin_amdgcn_mov_dpp(__float_as_int(v),0xB1,0xF,0xF,true));
  v += __int_as_float(__builtin_amdgcn_mov_dpp(__float_as_int(v),0x4E,0xF,0xF,true));
  return v;
}
static __device__ __forceinline__ float rsum4(float v){
  return v + __int_as_float(__builtin_amdgcn_ds_swizzle(__float_as_int(v), 0x101F));
}
static __device__ __forceinline__ float sel4(int c, float4 v){
  float r=v.x; r=(c==1)?v.y:r; r=(c==2)?v.z:r; r=(c==3)?v.w:r; return r;
}

// A-fragment pair (hi/lo split), per-gate tiling: rows tile*16..+15 of gate.
// mfma_f32_16x16x32_bf16 A layout: lane l holds A[m=l&15][k=(l>>4)*8+j].
static __device__ __forceinline__ void load_afrag(const float* __restrict__ whh,
                                                  int gate, int tile, int l, int kc,
                                                  s16x8& hi, s16x8& lo){
  const int r  = tile*16 + (l & 15);           // row within gate (>=100 -> 0)
  const int kb = kc*32 + (l >> 4)*8;
  #pragma unroll
  for (int j = 0; j < 8; ++j){
    const int k = kb + j;
    const float wv = (r < 100 && k < 100) ? whh[(size_t)(gate*100 + r)*100 + k] : 0.0f;
    const unsigned short hb = f2bf(wv);
    hi[j] = (short)hb;
    lo[j] = (short)f2bf(wv - bf2f(hb));
  }
}

// ---------------------------------------------------------------------------
// L1 (MFMA, 4 waves, fused finalize): I=1, H=100, 512 steps, 16 chains/block,
// 128 blocks (64 fwd + 64 bwd), 256 threads = 4 waves (1/SIMD). Gates padded
// to 128 rows = 8 tiles; wave W owns tiles {2W,2W+1} of all 3 gates (tile 7
// pure pad). Per wave: 6 C-frags, 72 MFMA, 8 GRU cells/lane. B-frag LDS reads
// 32/step total (was 56). cvt_pk bf16 packing. ONE barrier/step.
// ---------------------------------------------------------------------------
__global__ __launch_bounds__(256, 1)
void gru_l1(const float* __restrict__ data,
            const float* __restrict__ wih_f, const float* __restrict__ whh_f,
            const float* __restrict__ bih_f, const float* __restrict__ bhh_f,
            const float* __restrict__ wih_b, const float* __restrict__ whh_b,
            const float* __restrict__ bih_b, const float* __restrict__ bhh_b,
            float* __restrict__ x1f, float* __restrict__ x1b,
            float* __restrict__ out)
{
  const int dir   = (int)(blockIdx.x >> 6);
  const int blk16 = (int)(blockIdx.x & 63);
  const int t     = (int)threadIdx.x;
  const float* __restrict__ wih = dir ? wih_b : wih_f;
  const float* __restrict__ whh = dir ? whh_b : whh_f;
  const float* __restrict__ bih = dir ? bih_b : bih_f;
  const float* __restrict__ bhh = dir ? bhh_b : bhh_f;
  float* __restrict__ x1 = dir ? x1b : x1f;
  const int obase = dir ? 200 : 0;
  const int b0 = blk16 * 16;

  __shared__ __align__(16) unsigned short hBhi[2][16][136]; // [buf][chain][k]
  __shared__ __align__(16) unsigned short hBlo[2][16][136];
  __shared__ __align__(16) float xs[512][16];               // [step][chain], dir-adjusted

  for (int i = t; i < 8192; i += 256){
    const int c  = i >> 9;
    const int sL = i & 511;
    xs[sL][c] = data[(size_t)(b0 + c)*512 + (size_t)(dir ? (511 - sL) : sL)];
  }
  { unsigned short* ph = (unsigned short*)hBhi;
    unsigned short* pl = (unsigned short*)hBlo;
    for (int i = t; i < 2*16*136; i += 256){ ph[i] = 0; pl[i] = 0; } }

  const int l  = t & 63;
  const int W  = t >> 6;   // wave 0..3
  const int tA = 2*W, tB = 2*W + 1;

  // A-fragments: 3 gates x 2 tiles x 4 kc x (hi,lo) = 48 frags (192 regs)
  #define DECLA(G,T) s16x8 AH##G##T##0, AH##G##T##1, AH##G##T##2, AH##G##T##3, \
                           AL##G##T##0, AL##G##T##1, AL##G##T##2, AL##G##T##3;
  DECLA(0,a) DECLA(1,a) DECLA(2,a) DECLA(0,b) DECLA(1,b) DECLA(2,b)
  #undef DECLA
  #define LDA(G,T,TI) \
    load_afrag(whh, G, TI, l, 0, AH##G##T##0, AL##G##T##0); \
    load_afrag(whh, G, TI, l, 1, AH##G##T##1, AL##G##T##1); \
    load_afrag(whh, G, TI, l, 2, AH##G##T##2, AL##G##T##2); \
    load_afrag(whh, G, TI, l, 3, AH##G##T##3, AL##G##T##3);
  LDA(0,a,tA) LDA(1,a,tA) LDA(2,a,tA)
  LDA(0,b,tB) LDA(1,b,tB) LDA(2,b,tB)
  #undef LDA

  // per-lane finalize constants: tiles A and B, units uX0..uX0+3, chain c
  const int mg  = (l >> 4) * 4;
  const int c   = l & 15;
  const int uA0 = tA*16 + mg;
  const int uB0 = tB*16 + mg;
  const bool vA = (uA0 < 100);
  const bool vB = (uB0 < 100);
  const int uA = vA ? uA0 : 96;
  const int uB = vB ? uB0 : 96;
  const f32x4 wxrA = *(const f32x4*)&wih[uA];
  const f32x4 wxzA = *(const f32x4*)&wih[100 + uA];
  const f32x4 wxnA = *(const f32x4*)&wih[200 + uA];
  const f32x4 bcrA = *(const f32x4*)&bih[uA]       + *(const f32x4*)&bhh[uA];
  const f32x4 bczA = *(const f32x4*)&bih[100 + uA] + *(const f32x4*)&bhh[100 + uA];
  const f32x4 bxnA = *(const f32x4*)&bih[200 + uA];
  const f32x4 bhnA = *(const f32x4*)&bhh[200 + uA];
  const f32x4 wxrB = *(const f32x4*)&wih[uB];
  const f32x4 wxzB = *(const f32x4*)&wih[100 + uB];
  const f32x4 wxnB = *(const f32x4*)&wih[200 + uB];
  const f32x4 bcrB = *(const f32x4*)&bih[uB]       + *(const f32x4*)&bhh[uB];
  const f32x4 bczB = *(const f32x4*)&bih[100 + uB] + *(const f32x4*)&bhh[100 + uB];
  const f32x4 bxnB = *(const f32x4*)&bih[200 + uB];
  const f32x4 bhnB = *(const f32x4*)&bhh[200 + uB];
  f32x4 hpA = {0.f,0.f,0.f,0.f};
  f32x4 hpB = {0.f,0.f,0.f,0.f};

  // incremental x1 store pointers (layout unchanged: ((cs*256+(ch>>2))*100+u)*4+(ch&3))
  const int ch = b0 + c;
  float* pA = x1 + ((size_t)(ch >> 2)*100 + uA0)*4 + (ch & 3);
  float* pB = x1 + ((size_t)(ch >> 2)*100 + uB0)*4 + (ch & 3);
  const size_t CSSTRIDE = (size_t)256*100*4;

  __syncthreads();

  const int bn = c;             // B-frag: chain
  const int bg = (l >> 4)*8;    // B-frag: k offset within chunk

  #pragma unroll 2
  for (int s = 0; s < 512; ++s){
    const int cur = s & 1, nxt = cur ^ 1;
    const float xc = xs[s][c];

    // ---- B fragments (shared h, bf16 hi/lo) ----
    const s16x8 BH0 = *(const s16x8*)&hBhi[cur][bn][ 0 + bg];
    const s16x8 BL0 = *(const s16x8*)&hBlo[cur][bn][ 0 + bg];
    const s16x8 BH1 = *(const s16x8*)&hBhi[cur][bn][32 + bg];
    const s16x8 BL1 = *(const s16x8*)&hBlo[cur][bn][32 + bg];
    const s16x8 BH2 = *(const s16x8*)&hBhi[cur][bn][64 + bg];
    const s16x8 BL2 = *(const s16x8*)&hBlo[cur][bn][64 + bg];
    const s16x8 BH3 = *(const s16x8*)&hBhi[cur][bn][96 + bg];
    const s16x8 BL3 = *(const s16x8*)&hBlo[cur][bn][96 + bg];

    // ---- MFMA: 6 C-frags (3 gates x 2 tiles), 3-term split ----
    f32x4 C0a={0.f,0.f,0.f,0.f}, C1a={0.f,0.f,0.f,0.f}, C2a={0.f,0.f,0.f,0.f};
    f32x4 C0b={0.f,0.f,0.f,0.f}, C1b={0.f,0.f,0.f,0.f}, C2b={0.f,0.f,0.f,0.f};
    #define MM3(ACC,AH,AL,BH,BL) \
      ACC = __builtin_amdgcn_mfma_f32_16x16x32_bf16(AL, BH, ACC, 0, 0, 0); \
      ACC = __builtin_amdgcn_mfma_f32_16x16x32_bf16(AH, BL, ACC, 0, 0, 0); \
      ACC = __builtin_amdgcn_mfma_f32_16x16x32_bf16(AH, BH, ACC, 0, 0, 0);
    #define MMKC(KC) \
      MM3(C0a, AH0a##KC, AL0a##KC, BH##KC, BL##KC) \
      MM3(C1a, AH1a##KC, AL1a##KC, BH##KC, BL##KC) \
      MM3(C2a, AH2a##KC, AL2a##KC, BH##KC, BL##KC) \
      MM3(C0b, AH0b##KC, AL0b##KC, BH##KC, BL##KC) \
      MM3(C1b, AH1b##KC, AL1b##KC, BH##KC, BL##KC) \
      MM3(C2b, AH2b##KC, AL2b##KC, BH##KC, BL##KC)
    MMKC(0) MMKC(1) MMKC(2) MMKC(3)
    #undef MMKC
    #undef MM3

    // ---- fused finalize: tile A (4 cells) + tile B (4 cells) ----
    f32x4 hnA, hnB;
    #define FIN(I,SR,SZ,SN,WXR,WXZ,WXN,BCR,BCZ,BXN,BHN,HP,HN) { \
      const float rr = sigf(SR[I] + fmaf(WXR[I], xc, BCR[I])); \
      const float zz = sigf(SZ[I] + fmaf(WXZ[I], xc, BCZ[I])); \
      const float nn = tanhf_fast(fmaf(WXN[I], xc, BXN[I]) + rr*(SN[I] + BHN[I])); \
      HN[I] = nn + zz*(HP[I] - nn); }
    FIN(0,C0a,C1a,C2a,wxrA,wxzA,wxnA,bcrA,bczA,bxnA,bhnA,hpA,hnA)
    FIN(1,C0a,C1a,C2a,wxrA,wxzA,wxnA,bcrA,bczA,bxnA,bhnA,hpA,hnA)
    FIN(2,C0a,C1a,C2a,wxrA,wxzA,wxnA,bcrA,bczA,bxnA,bhnA,hpA,hnA)
    FIN(3,C0a,C1a,C2a,wxrA,wxzA,wxnA,bcrA,bczA,bxnA,bhnA,hpA,hnA)
    FIN(0,C0b,C1b,C2b,wxrB,wxzB,wxnB,bcrB,bczB,bxnB,bhnB,hpB,hnB)
    FIN(1,C0b,C1b,C2b,wxrB,wxzB,wxnB,bcrB,bczB,bxnB,bhnB,hpB,hnB)
    FIN(2,C0b,C1b,C2b,wxrB,wxzB,wxnB,bcrB,bczB,bxnB,bhnB,hpB,hnB)
    FIN(3,C0b,C1b,C2b,wxrB,wxzB,wxnB,bcrB,bczB,bxnB,bhnB,hpB,hnB)
    #undef FIN
    hpA = hnA; hpB = hnB;

    // ---- pack bf16 hi/lo via cvt_pk; lo self-corrects against actual hi bits ----
    if (vA){
      const unsigned int px = cvt_pk_bf16(hnA[0], hnA[1]);
      const unsigned int py = cvt_pk_bf16(hnA[2], hnA[3]);
      const float l0 = hnA[0] - __uint_as_float(px << 16);
      const float l1 = hnA[1] - __uint_as_float(px & 0xFFFF0000u);
      const float l2 = hnA[2] - __uint_as_float(py << 16);
      const float l3 = hnA[3] - __uint_as_float(py & 0xFFFF0000u);
      uint2 vhi; vhi.x = px; vhi.y = py;
      uint2 vlo; vlo.x = cvt_pk_bf16(l0, l1); vlo.y = cvt_pk_bf16(l2, l3);
      *(uint2*)&hBhi[nxt][c][uA0] = vhi;
      *(uint2*)&hBlo[nxt][c][uA0] = vlo;
    }
    if (vB){
      const unsigned int px = cvt_pk_bf16(hnB[0], hnB[1]);
      const unsigned int py = cvt_pk_bf16(hnB[2], hnB[3]);
      const float l0 = hnB[0] - __uint_as_float(px << 16);
      const float l1 = hnB[1] - __uint_as_float(px & 0xFFFF0000u);
      const float l2 = hnB[2] - __uint_as_float(py << 16);
      const float l3 = hnB[3] - __uint_as_float(py & 0xFFFF0000u);
      uint2 vhi; vhi.x = px; vhi.y = py;
      uint2 vlo; vlo.x = cvt_pk_bf16(l0, l1); vlo.y = cvt_pk_bf16(l2, l3);
      *(uint2*)&hBhi[nxt][c][uB0] = vhi;
      *(uint2*)&hBlo[nxt][c][uB0] = vlo;
    }

    if ((s & 3) == 3){
      if (vA){ pA[0]=hnA[0]; pA[4]=hnA[1]; pA[8]=hnA[2]; pA[12]=hnA[3]; pA += CSSTRIDE; }
      if (vB){ pB[0]=hnB[0]; pB[4]=hnB[1]; pB[8]=hnB[2]; pB[12]=hnB[3]; pB += CSSTRIDE; }
    }
    if (s == 511){
      if (vA) *(f32x4*)&out[(size_t)ch*400 + obase + uA0] = hnA;
      if (vB) *(f32x4*)&out[(size_t)ch*400 + obase + uB0] = hnB;
    }
    __syncthreads();
  }
}

// ---------------------------------------------------------------------------
// L2: I=100, H=50, 128 steps, lane-3 chains, 4 chains/block, 512 blocks.
// (unchanged — verified correct)
// ---------------------------------------------------------------------------
__global__ __launch_bounds__(512, 4)
void gru_l2(const float* __restrict__ x1f, const float* __restrict__ x1b,
            const float* __restrict__ wih_f, const float* __restrict__ whh_f,
            const float* __restrict__ bih_f, const float* __restrict__ bhh_f,
            const float* __restrict__ wih_b, const float* __restrict__ whh_b,
            const float* __restrict__ bih_b, const float* __restrict__ bhh_b,
            float* __restrict__ x2f, float* __restrict__ x2b,
            float* __restrict__ out)
{
  const int dir = (int)(blockIdx.x >> 8);
  const int blk = (int)(blockIdx.x & 255);
  const int t   = (int)threadIdx.x;
  const float* __restrict__ wih = dir ? wih_b : wih_f;
  const float* __restrict__ whh = dir ? whh_b : whh_f;
  const float* __restrict__ bih = dir ? bih_b : bih_f;
  const float* __restrict__ bhh = dir ? bhh_b : bhh_f;
  const float* __restrict__ x1 = dir ? x1b : x1f;
  float* __restrict__ x2 = dir ? x2b : x2f;
  const int obase = dir ? 300 : 100;
  const int b0 = blk * 4;

  __shared__ __align__(16) float xh[2][152][4];

  const int oct = t >> 3;
  const int u   = (oct > 49) ? 49 : oct;
  const int l   = t & 7;
  const int cb  = 19 * l;           // combined col base (0..133)
  float4 W0,W1,W2,W3,W4,W5,W6,W7,W8,W9,W10,W11,W12,W13,W14,W15,W16,W17,W18;
  #define L2LW(J, V) { const int g = cb + (J); \
    const float wr_ = (g<100) ? wih[(size_t)(u     )*100+g] : ((g<150)? whh[(size_t)(u     )*50+g-100] : 0.f); \
    const float wz_ = (g<100) ? wih[(size_t)(u + 50)*100+g] : ((g<150)? whh[(size_t)(u + 50)*50+g-100] : 0.f); \
    const float wx_ = (g<100) ? wih[(size_t)(u +100)*100+g] : 0.f; \
    const float wh_ = (g>=100 && g<150) ? whh[(size_t)(u +100)*50+g-100] : 0.f; \
    V = make_float4(wr_, wz_, wx_, wh_); }
  L2LW(0,W0)  L2LW(1,W1)  L2LW(2,W2)  L2LW(3,W3)  L2LW(4,W4)  L2LW(5,W5)  L2LW(6,W6)
  L2LW(7,W7)  L2LW(8,W8)  L2LW(9,W9)  L2LW(10,W10) L2LW(11,W11) L2LW(12,W12) L2LW(13,W13)
  L2LW(14,W14) L2LW(15,W15) L2LW(16,W16) L2LW(17,W17) L2LW(18,W18)
  #undef L2LW
  const float bcr = bih[u] + bhh[u];
  const float bcz = bih[u+50] + bhh[u+50];
  const float bxn = bih[u+100];
  const float bhn = bhh[u+100];

  for (int i = t; i < 104; i += 512){            // zero h rows + pads, both buffers
    const int bi = (i >= 52) ? 1 : 0;
    const int row = 100 + (i - bi*52);
    *(float4*)&xh[bi][row][0] = make_float4(0.f,0.f,0.f,0.f);
  }
  if (t < 100)                                    // stage x for step 0
    *(float4*)&xh[0][t][0] = *(const float4*)(x1 + (((size_t)0*256 + blk)*100 + t)*4);
  __syncthreads();

  #pragma unroll 1
  for (int s = 0; s < 128; ++s){
    const int cur = s & 1, nxt = cur ^ 1;
    if (t < 400){
      const float* hb = &xh[cur][cb][0];
      float ar0=0,ar1=0,ar2=0,ar3=0, az0=0,az1=0,az2=0,az3=0;
      float ax0=0,ax1=0,ax2=0,ax3=0, ah0=0,ah1=0,ah2=0,ah3=0;
      #define L2C(J, WV) { const float4 h4 = *(const float4*)(hb + 4*(J)); \
        ar0=fmaf(WV.x,h4.x,ar0); ar1=fmaf(WV.x,h4.y,ar1); ar2=fmaf(WV.x,h4.z,ar2); ar3=fmaf(WV.x,h4.w,ar3); \
        az0=fmaf(WV.y,h4.x,az0); az1=fmaf(WV.y,h4.y,az1); az2=fmaf(WV.y,h4.z,az2); az3=fmaf(WV.y,h4.w,az3); \
        ax0=fmaf(WV.z,h4.x,ax0); ax1=fmaf(WV.z,h4.y,ax1); ax2=fmaf(WV.z,h4.z,ax2); ax3=fmaf(WV.z,h4.w,ax3); \
        ah0=fmaf(WV.w,h4.x,ah0); ah1=fmaf(WV.w,h4.y,ah1); ah2=fmaf(WV.w,h4.z,ah2); ah3=fmaf(WV.w,h4.w,ah3); }
      L2C(0,W0)  L2C(1,W1)  L2C(2,W2)  L2C(3,W3)  L2C(4,W4)  L2C(5,W5)  L2C(6,W6)
      L2C(7,W7)  L2C(8,W8)  L2C(9,W9)  L2C(10,W10) L2C(11,W11) L2C(12,W12) L2C(13,W13)
      L2C(14,W14) L2C(15,W15) L2C(16,W16) L2C(17,W17) L2C(18,W18)
      #undef L2C
      ar0=qsum(ar0); ar1=qsum(ar1); ar2=qsum(ar2); ar3=qsum(ar3);
      az0=qsum(az0); az1=qsum(az1); az2=qsum(az2); az3=qsum(az3);
      ax0=qsum(ax0); ax1=qsum(ax1); ax2=qsum(ax2); ax3=qsum(ax3);
      ah0=qsum(ah0); ah1=qsum(ah1); ah2=qsum(ah2); ah3=qsum(ah3);
      ar0=rsum4(ar0); ar1=rsum4(ar1); ar2=rsum4(ar2); ar3=rsum4(ar3);
      az0=rsum4(az0); az1=rsum4(az1); az2=rsum4(az2); az3=rsum4(az3);
      ax0=rsum4(ax0); ax1=rsum4(ax1); ax2=rsum4(ax2); ax3=rsum4(ax3);
      ah0=rsum4(ah0); ah1=rsum4(ah1); ah2=rsum4(ah2); ah3=rsum4(ah3);
      if (l < 4){
        const float Ar = sel4(l, make_float4(ar0,ar1,ar2,ar3));
        const float Az = sel4(l, make_float4(az0,az1,az2,az3));
        const float Ax = sel4(l, make_float4(ax0,ax1,ax2,ax3));
        const float Ah = sel4(l, make_float4(ah0,ah1,ah2,ah3));
        const float ho = xh[cur][100+u][l];
        const float r = sigf(Ar + bcr);
        const float z = sigf(Az + bcz);
        const float n = tanhf_fast(Ax + bxn + r*(Ah + bhn));
        const float hnew = n + z*(ho - n);
        xh[nxt][100+u][l] = hnew;
        if ((s & 3) == 3) x2[(((size_t)(s>>2)*256 + blk)*50 + u)*4 + l] = hnew;
        if (s == 127)     out[(size_t)(b0 + l)*400 + obase + u] = hnew;
      }
    } else if (t < 500){
      if (s + 1 < 128){
        const int j = t - 400;
        *(float4*)&xh[nxt][j][0] = *(const float4*)(x1 + (((size_t)(s+1)*256 + blk)*100 + j)*4);
      }
    }
    __syncthreads();
  }
}

// ---------------------------------------------------------------------------
// L3: I=50, H=50, 32 steps, lane-15 chains. (unchanged — verified correct)
// ---------------------------------------------------------------------------
__global__ __launch_bounds__(512, 4)
void gru_l3(const float* __restrict__ x2f, const float* __restrict__ x2b,
            const float* __restrict__ wih_f, const float* __restrict__ whh_f,
            const float* __restrict__ bih_f, const float* __restrict__ bhh_f,
            const float* __restrict__ wih_b, const float* __restrict__ whh_b,
            const float* __restrict__ bih_b, const float* __restrict__ bhh_b,
            float* __restrict__ out)
{
  const int dir = (int)(blockIdx.x >> 8);
  const int blk = (int)(blockIdx.x & 255);
  const int t   = (int)threadIdx.x;
  const float* __restrict__ wih = dir ? wih_b : wih_f;
  const float* __restrict__ whh = dir ? whh_b : whh_f;
  const float* __restrict__ bih = dir ? bih_b : bih_f;
  const float* __restrict__ bhh = dir ? bhh_b : bhh_f;
  const float* __restrict__ x2 = dir ? x2b : x2f;
  const int obase = dir ? 350 : 150;
  const int b0 = blk * 4;

  __shared__ __align__(16) float xh[2][104][4];

  const int oct = t >> 3;
  const int u   = (oct > 49) ? 49 : oct;
  const int l   = t & 7;
  const int cb  = 13 * l;           // 0..91
  float4 W0,W1,W2,W3,W4,W5,W6,W7,W8,W9,W10,W11,W12;
  #define L3LW(J, V) { const int g = cb + (J); \
    const float wr_ = (g<50) ? wih[(size_t)(u     )*50+g] : ((g<100)? whh[(size_t)(u     )*50+g-50] : 0.f); \
    const float wz_ = (g<50) ? wih[(size_t)(u + 50)*50+g] : ((g<100)? whh[(size_t)(u + 50)*50+g-50] : 0.f); \
    const float wx_ = (g<50) ? wih[(size_t)(u +100)*50+g] : 0.f; \
    const float wh_ = (g>=50 && g<100) ? whh[(size_t)(u +100)*50+g-50] : 0.f; \
    V = make_float4(wr_, wz_, wx_, wh_); }
  L3LW(0,W0) L3LW(1,W1) L3LW(2,W2) L3LW(3,W3) L3LW(4,W4) L3LW(5,W5) L3LW(6,W6)
  L3LW(7,W7) L3LW(8,W8) L3LW(9,W9) L3LW(10,W10) L3LW(11,W11) L3LW(12,W12)
  #undef L3LW
  const float bcr = bih[u] + bhh[u];
  const float bcz = bih[u+50] + bhh[u+50];
  const float bxn = bih[u+100];
  const float bhn = bhh[u+100];

  for (int i = t; i < 108; i += 512){            // zero h rows + pads, both buffers
    const int bi = (i >= 54) ? 1 : 0;
    const int row = 50 + (i - bi*54);
    *(float4*)&xh[bi][row][0] = make_float4(0.f,0.f,0.f,0.f);
  }
  if (t < 50)
    *(float4*)&xh[0][t][0] = *(const float4*)(x2 + (((size_t)0*256 + blk)*50 + t)*4);
  __syncthreads();

  #pragma unroll 1
  for (int s = 0; s < 32; ++s){
    const int cur = s & 1, nxt = cur ^ 1;
    if (t < 400){
      const float* hb = &xh[cur][cb][0];
      float ar0=0,ar1=0,ar2=0,ar3=0, az0=0,az1=0,az2=0,az3=0;
      float ax0=0,ax1=0,ax2=0,ax3=0, ah0=0,ah1=0,ah2=0,ah3=0;
      #define L3C(J, WV) { const float4 h4 = *(const float4*)(hb + 4*(J)); \
        ar0=fmaf(WV.x,h4.x,ar0); ar1=fmaf(WV.x,h4.y,ar1); ar2=fmaf(WV.x,h4.z,ar2); ar3=fmaf(WV.x,h4.w,ar3); \
        az0=fmaf(WV.y,h4.x,az0); az1=fmaf(WV.y,h4.y,az1); az2=fmaf(WV.y,h4.z,az2); az3=fmaf(WV.y,h4.w,az3); \
        ax0=fmaf(WV.z,h4.x,ax0); ax1=fmaf(WV.z,h4.y,ax1); ax2=fmaf(WV.z,h4.z,ax2); ax3=fmaf(WV.z,h4.w,ax3); \
        ah0=fmaf(WV.w,h4.x,ah0); ah1=fmaf(WV.w,h4.y,ah1); ah2=fmaf(WV.w,h4.z,ah2); ah3=fmaf(WV.w,h4.w,ah3); }
      L3C(0,W0) L3C(1,W1) L3C(2,W2) L3C(3,W3) L3C(4,W4) L3C(5,W5) L3C(6,W6)
      L3C(7,W7) L3C(8,W8) L3C(9,W9) L3C(10,W10) L3C(11,W11) L3C(12,W12)
      #undef L3C
      ar0=qsum(ar0); ar1=qsum(ar1); ar2=qsum(ar2); ar3=qsum(ar3);
      az0=qsum(az0); az1=qsum(az1); az2=qsum(az2); az3=qsum(az3);
      ax0=qsum(ax0); ax1=qsum(ax1); ax2=qsum(ax2); ax3=qsum(ax3);
      ah0=qsum(ah0); ah1=qsum(ah1); ah2=qsum(ah2); ah3=qsum(ah3);
      ar0=rsum4(ar0); ar1=rsum4(ar1); ar2=rsum4(ar2); ar3=rsum4(ar3);
      az0=rsum4(az0); az1=rsum4(az1); az2=rsum4(az2); az3=rsum4(az3);
      ax0=rsum4(ax0); ax1=rsum4(ax1); ax2=rsum4(ax2); ax3=rsum4(ax3);
      ah0=rsum4(ah0); ah1=rsum4(ah1); ah2=rsum4(ah2); ah3=rsum4(ah3);
      if (l < 4){
        const float Ar = sel4(l, make_float4(ar0,ar1,ar2,ar3));
        const float Az = sel4(l, make_float4(az0,az1,az2,az3));
        const float Ax = sel4(l, make_float4(ax0,ax1,ax2,ax3));
        const float Ah = sel4(l, make_float4(ah0,ah1,ah2,ah3));
        const float ho = xh[cur][50+u][l];
        const float r = sigf(Ar + bcr);
        const float z = sigf(Az + bcz);
        const float n = tanhf_fast(Ax + bxn + r*(Ah + bhn));
        const float hnew = n + z*(ho - n);
        xh[nxt][50+u][l] = hnew;
        if (s == 31) out[(size_t)(b0 + l)*400 + obase + u] = hnew;
      }
    } else if (t < 450){
      if (s + 1 < 32){
        const int j = t - 400;
        *(float4*)&xh[nxt][j][0] = *(const float4*)(x2 + (((size_t)(s+1)*256 + blk)*50 + j)*4);
      }
    }
    __syncthreads();
  }
}

extern "C" void kernel_launch(void* const* d_in, const int* in_sizes, int n_in,
                              void* d_out, int out_size, void* d_ws, size_t ws_size,
                              hipStream_t stream)
{
  const float* data   = (const float*)d_in[0];
  const float* f1_wih = (const float*)d_in[1];
  const float* f1_whh = (const float*)d_in[2];
  const float* f1_bih = (const float*)d_in[3];
  const float* f1_bhh = (const float*)d_in[4];
  const float* f2_wih = (const float*)d_in[5];
  const float* f2_whh = (const float*)d_in[6];
  const float* f2_bih = (const float*)d_in[7];
  const float* f2_bhh = (const float*)d_in[8];
  const float* f3_wih = (const float*)d_in[9];
  const float* f3_whh = (const float*)d_in[10];
  const float* f3_bih = (const float*)d_in[11];
  const float* f3_bhh = (const float*)d_in[12];
  const float* b1_wih = (const float*)d_in[13];
  const float* b1_whh = (const float*)d_in[14];
  const float* b1_bih = (const float*)d_in[15];
  const float* b1_bhh = (const float*)d_in[16];
  const float* b2_wih = (const float*)d_in[17];
  const float* b2_whh = (const float*)d_in[18];
  const float* b2_bih = (const float*)d_in[19];
  const float* b2_bhh = (const float*)d_in[20];
  const float* b3_wih = (const float*)d_in[21];
  const float* b3_whh = (const float*)d_in[22];
  const float* b3_bih = (const float*)d_in[23];
  const float* b3_bhh = (const float*)d_in[24];
  float* out = (float*)d_out;

  const size_t X1N = (size_t)128 * 256 * 100 * 4;  // [cs][blk][unit][chain]
  const size_t X2N = (size_t)32 * 256 * 50 * 4;    // [k2][blk][unit][chain]
  if (ws_size < (2 * X1N + 2 * X2N) * sizeof(float)) return;
  float* wsf = (float*)d_ws;
  float* x1f = wsf;
  float* x1b = wsf + X1N;
  float* x2f = wsf + 2 * X1N;
  float* x2b = wsf + 2 * X1N + X2N;

  gru_l1<<<dim3(128), dim3(256), 0, stream>>>(
      data, f1_wih, f1_whh, f1_bih, f1_bhh,
      b1_wih, b1_whh, b1_bih, b1_bhh, x1f, x1b, out);
  gru_l2<<<dim3(512), dim3(512), 0, stream>>>(
      x1f, x1b, f2_wih, f2_whh, f2_bih, f2_bhh,
      b2_wih, b2_whh, b2_bih, b2_bhh, x2f, x2b, out);
  gru_l3<<<dim3(512), dim3(512), 0, stream>>>(
      x2f, x2b, f3_wih, f3_whh, f3_bih, f3_bhh,
      b3_wih, b3_whh, b3_bih, b3_bhh, out);
}

// Round 10
// 1217.812 us; speedup vs baseline: 1.0039x; 1.0039x over previous
//
#include <hip/hip_runtime.h>
#include <math.h>

typedef short  s16x8 __attribute__((ext_vector_type(8)));   // 8 bf16 bit-patterns (4 VGPRs)
typedef float  f32x4 __attribute__((ext_vector_type(4)));

static __device__ __forceinline__ float sigf(float x){ return 1.0f/(1.0f+__expf(-x)); }
static __device__ __forceinline__ float tanhf_fast(float x){
  float ax=fabsf(x); float e=__expf(-2.0f*ax); float t=(1.0f-e)/(1.0f+e); return copysignf(t,x);
}
static __device__ __forceinline__ unsigned short f2bf(float x){  // RNE f32->bf16 bits (A-frag prep)
  unsigned int u = __float_as_uint(x);
  unsigned int r = (u + 0x7FFFu + ((u >> 16) & 1u)) >> 16;
  return (unsigned short)r;
}
static __device__ __forceinline__ float bf2f(unsigned short b){
  return __uint_as_float(((unsigned int)b) << 16);
}
// packed f32x2 -> bf16x2; lo term computed from ACTUAL hi bits => split self-corrects.
static __device__ __forceinline__ unsigned int cvt_pk_bf16(float a, float b){
  unsigned int r;
  asm("v_cvt_pk_bf16_f32 %0, %1, %2" : "=v"(r) : "v"(a), "v"(b));
  return r;
}
// barrier without vmcnt drain: LDS writes ordered, global stores stay in flight
// (m201-verified raw-barrier pattern; x1/out consumers are later kernels).
static __device__ __forceinline__ void fast_barrier(){
  asm volatile("s_waitcnt lgkmcnt(0)" ::: "memory");
  __builtin_amdgcn_s_barrier();
}
// quad/octet reduce helpers (verified r4) — used by L2/L3
static __device__ __forceinline__ float qsum(float v){
  v += __int_as_float(__builtin_amdgcn_mov_dpp(__float_as_int(v),0xB1,0xF,0xF,true));
  v += __int_as_float(__builtin_amdgcn_mov_dpp(__float_as_int(v),0x4E,0xF,0xF,true));
  return v;
}
static __device__ __forceinline__ float rsum4(float v){
  return v + __int_as_float(__builtin_amdgcn_ds_swizzle(__float_as_int(v), 0x101F));
}
static __device__ __forceinline__ float sel4(int c, float4 v){
  float r=v.x; r=(c==1)?v.y:r; r=(c==2)?v.z:r; r=(c==3)?v.w:r; return r;
}

// A-fragment pair (hi/lo split), per-gate tiling: rows tile*16..+15 of gate.
// mfma_f32_16x16x32_bf16 A layout: lane l holds A[m=l&15][k=(l>>4)*8+j].
static __device__ __forceinline__ void load_afrag(const float* __restrict__ whh,
                                                  int gate, int tile, int l, int kc,
                                                  s16x8& hi, s16x8& lo){
  const int r  = tile*16 + (l & 15);           // row within gate (>=100 -> 0)
  const int kb = kc*32 + (l >> 4)*8;
  #pragma unroll
  for (int j = 0; j < 8; ++j){
    const int k = kb + j;
    const float wv = (r < 100 && k < 100) ? whh[(size_t)(gate*100 + r)*100 + k] : 0.0f;
    const unsigned short hb = f2bf(wv);
    hi[j] = (short)hb;
    lo[j] = (short)f2bf(wv - bf2f(hb));
  }
}

// ---------------------------------------------------------------------------
// L1 (MFMA, 4 waves, fused finalize): I=1, H=100, 512 steps, 16 chains/block,
// 128 blocks (64 fwd + 64 bwd), 256 threads = 4 waves (1/SIMD). Gates padded
// to 128 rows = 8 tiles; wave W owns tiles {2W,2W+1} of all 3 gates. Per
// wave: 6 C-frags, 72 MFMA term-major-interleaved (dep distance 6). Raw
// barrier (no vmcnt drain) — x1/out stores stay in flight. ONE barrier/step.
// ---------------------------------------------------------------------------
__global__ __launch_bounds__(256, 1)
void gru_l1(const float* __restrict__ data,
            const float* __restrict__ wih_f, const float* __restrict__ whh_f,
            const float* __restrict__ bih_f, const float* __restrict__ bhh_f,
            const float* __restrict__ wih_b, const float* __restrict__ whh_b,
            const float* __restrict__ bih_b, const float* __restrict__ bhh_b,
            float* __restrict__ x1f, float* __restrict__ x1b,
            float* __restrict__ out)
{
  const int dir   = (int)(blockIdx.x >> 6);
  const int blk16 = (int)(blockIdx.x & 63);
  const int t     = (int)threadIdx.x;
  const float* __restrict__ wih = dir ? wih_b : wih_f;
  const float* __restrict__ whh = dir ? whh_b : whh_f;
  const float* __restrict__ bih = dir ? bih_b : bih_f;
  const float* __restrict__ bhh = dir ? bhh_b : bhh_f;
  float* __restrict__ x1 = dir ? x1b : x1f;
  const int obase = dir ? 200 : 0;
  const int b0 = blk16 * 16;

  __shared__ __align__(16) unsigned short hBhi[2][16][136]; // [buf][chain][k]
  __shared__ __align__(16) unsigned short hBlo[2][16][136];
  __shared__ __align__(16) float xs[512][16];               // [step][chain], dir-adjusted

  for (int i = t; i < 8192; i += 256){
    const int c  = i >> 9;
    const int sL = i & 511;
    xs[sL][c] = data[(size_t)(b0 + c)*512 + (size_t)(dir ? (511 - sL) : sL)];
  }
  { unsigned short* ph = (unsigned short*)hBhi;
    unsigned short* pl = (unsigned short*)hBlo;
    for (int i = t; i < 2*16*136; i += 256){ ph[i] = 0; pl[i] = 0; } }

  const int l  = t & 63;
  const int W  = t >> 6;   // wave 0..3
  const int tA = 2*W, tB = 2*W + 1;

  // A-fragments: 3 gates x 2 tiles x 4 kc x (hi,lo) = 48 frags (192 regs)
  #define DECLA(G,T) s16x8 AH##G##T##0, AH##G##T##1, AH##G##T##2, AH##G##T##3, \
                           AL##G##T##0, AL##G##T##1, AL##G##T##2, AL##G##T##3;
  DECLA(0,a) DECLA(1,a) DECLA(2,a) DECLA(0,b) DECLA(1,b) DECLA(2,b)
  #undef DECLA
  #define LDA(G,T,TI) \
    load_afrag(whh, G, TI, l, 0, AH##G##T##0, AL##G##T##0); \
    load_afrag(whh, G, TI, l, 1, AH##G##T##1, AL##G##T##1); \
    load_afrag(whh, G, TI, l, 2, AH##G##T##2, AL##G##T##2); \
    load_afrag(whh, G, TI, l, 3, AH##G##T##3, AL##G##T##3);
  LDA(0,a,tA) LDA(1,a,tA) LDA(2,a,tA)
  LDA(0,b,tB) LDA(1,b,tB) LDA(2,b,tB)
  #undef LDA

  // per-lane finalize constants: tiles A and B, units uX0..uX0+3, chain c
  const int mg  = (l >> 4) * 4;
  const int c   = l & 15;
  const int uA0 = tA*16 + mg;
  const int uB0 = tB*16 + mg;
  const bool vA = (uA0 < 100);
  const bool vB = (uB0 < 100);
  const int uA = vA ? uA0 : 96;
  const int uB = vB ? uB0 : 96;
  const f32x4 wxrA = *(const f32x4*)&wih[uA];
  const f32x4 wxzA = *(const f32x4*)&wih[100 + uA];
  const f32x4 wxnA = *(const f32x4*)&wih[200 + uA];
  const f32x4 bcrA = *(const f32x4*)&bih[uA]       + *(const f32x4*)&bhh[uA];
  const f32x4 bczA = *(const f32x4*)&bih[100 + uA] + *(const f32x4*)&bhh[100 + uA];
  const f32x4 bxnA = *(const f32x4*)&bih[200 + uA];
  const f32x4 bhnA = *(const f32x4*)&bhh[200 + uA];
  const f32x4 wxrB = *(const f32x4*)&wih[uB];
  const f32x4 wxzB = *(const f32x4*)&wih[100 + uB];
  const f32x4 wxnB = *(const f32x4*)&wih[200 + uB];
  const f32x4 bcrB = *(const f32x4*)&bih[uB]       + *(const f32x4*)&bhh[uB];
  const f32x4 bczB = *(const f32x4*)&bih[100 + uB] + *(const f32x4*)&bhh[100 + uB];
  const f32x4 bxnB = *(const f32x4*)&bih[200 + uB];
  const f32x4 bhnB = *(const f32x4*)&bhh[200 + uB];
  f32x4 hpA = {0.f,0.f,0.f,0.f};
  f32x4 hpB = {0.f,0.f,0.f,0.f};

  // incremental x1 store pointers (layout: ((cs*256+(ch>>2))*100+u)*4+(ch&3))
  const int ch = b0 + c;
  float* pA = x1 + ((size_t)(ch >> 2)*100 + uA0)*4 + (ch & 3);
  float* pB = x1 + ((size_t)(ch >> 2)*100 + uB0)*4 + (ch & 3);
  const size_t CSSTRIDE = (size_t)256*100*4;

  __syncthreads();

  const int bn = c;             // B-frag: chain
  const int bg = (l >> 4)*8;    // B-frag: k offset within chunk

  #pragma unroll 2
  for (int s = 0; s < 512; ++s){
    const int cur = s & 1, nxt = cur ^ 1;
    const float xc = xs[s][c];   // read-only LDS; overlaps B-frag latency

    // ---- B fragments (shared h, bf16 hi/lo) ----
    const s16x8 BH0 = *(const s16x8*)&hBhi[cur][bn][ 0 + bg];
    const s16x8 BL0 = *(const s16x8*)&hBlo[cur][bn][ 0 + bg];
    const s16x8 BH1 = *(const s16x8*)&hBhi[cur][bn][32 + bg];
    const s16x8 BL1 = *(const s16x8*)&hBlo[cur][bn][32 + bg];
    const s16x8 BH2 = *(const s16x8*)&hBhi[cur][bn][64 + bg];
    const s16x8 BL2 = *(const s16x8*)&hBlo[cur][bn][64 + bg];
    const s16x8 BH3 = *(const s16x8*)&hBhi[cur][bn][96 + bg];
    const s16x8 BL3 = *(const s16x8*)&hBlo[cur][bn][96 + bg];

    // ---- MFMA: 6 C-frags, term-major interleave (dep distance 6) ----
    f32x4 C0a={0.f,0.f,0.f,0.f}, C1a={0.f,0.f,0.f,0.f}, C2a={0.f,0.f,0.f,0.f};
    f32x4 C0b={0.f,0.f,0.f,0.f}, C1b={0.f,0.f,0.f,0.f}, C2b={0.f,0.f,0.f,0.f};
    #define MF(ACC,A,B) ACC = __builtin_amdgcn_mfma_f32_16x16x32_bf16(A, B, ACC, 0, 0, 0);
    #define MMKC(KC) \
      MF(C0a, AL0a##KC, BH##KC) MF(C1a, AL1a##KC, BH##KC) MF(C2a, AL2a##KC, BH##KC) \
      MF(C0b, AL0b##KC, BH##KC) MF(C1b, AL1b##KC, BH##KC) MF(C2b, AL2b##KC, BH##KC) \
      MF(C0a, AH0a##KC, BL##KC) MF(C1a, AH1a##KC, BL##KC) MF(C2a, AH2a##KC, BL##KC) \
      MF(C0b, AH0b##KC, BL##KC) MF(C1b, AH1b##KC, BL##KC) MF(C2b, AH2b##KC, BL##KC) \
      MF(C0a, AH0a##KC, BH##KC) MF(C1a, AH1a##KC, BH##KC) MF(C2a, AH2a##KC, BH##KC) \
      MF(C0b, AH0b##KC, BH##KC) MF(C1b, AH1b##KC, BH##KC) MF(C2b, AH2b##KC, BH##KC)
    MMKC(0) MMKC(1) MMKC(2) MMKC(3)
    #undef MMKC
    #undef MF

    // ---- fused finalize: tile A (4 cells) + tile B (4 cells) ----
    f32x4 hnA, hnB;
    #define FIN(I,SR,SZ,SN,WXR,WXZ,WXN,BCR,BCZ,BXN,BHN,HP,HN) { \
      const float rr = sigf(SR[I] + fmaf(WXR[I], xc, BCR[I])); \
      const float zz = sigf(SZ[I] + fmaf(WXZ[I], xc, BCZ[I])); \
      const float nn = tanhf_fast(fmaf(WXN[I], xc, BXN[I]) + rr*(SN[I] + BHN[I])); \
      HN[I] = nn + zz*(HP[I] - nn); }
    FIN(0,C0a,C1a,C2a,wxrA,wxzA,wxnA,bcrA,bczA,bxnA,bhnA,hpA,hnA)
    FIN(1,C0a,C1a,C2a,wxrA,wxzA,wxnA,bcrA,bczA,bxnA,bhnA,hpA,hnA)
    FIN(2,C0a,C1a,C2a,wxrA,wxzA,wxnA,bcrA,bczA,bxnA,bhnA,hpA,hnA)
    FIN(3,C0a,C1a,C2a,wxrA,wxzA,wxnA,bcrA,bczA,bxnA,bhnA,hpA,hnA)
    FIN(0,C0b,C1b,C2b,wxrB,wxzB,wxnB,bcrB,bczB,bxnB,bhnB,hpB,hnB)
    FIN(1,C0b,C1b,C2b,wxrB,wxzB,wxnB,bcrB,bczB,bxnB,bhnB,hpB,hnB)
    FIN(2,C0b,C1b,C2b,wxrB,wxzB,wxnB,bcrB,bczB,bxnB,bhnB,hpB,hnB)
    FIN(3,C0b,C1b,C2b,wxrB,wxzB,wxnB,bcrB,bczB,bxnB,bhnB,hpB,hnB)
    #undef FIN
    hpA = hnA; hpB = hnB;

    // ---- pack bf16 hi/lo via cvt_pk; lo self-corrects against actual hi bits ----
    if (vA){
      const unsigned int px = cvt_pk_bf16(hnA[0], hnA[1]);
      const unsigned int py = cvt_pk_bf16(hnA[2], hnA[3]);
      const float l0 = hnA[0] - __uint_as_float(px << 16);
      const float l1 = hnA[1] - __uint_as_float(px & 0xFFFF0000u);
      const float l2 = hnA[2] - __uint_as_float(py << 16);
      const float l3 = hnA[3] - __uint_as_float(py & 0xFFFF0000u);
      uint2 vhi; vhi.x = px; vhi.y = py;
      uint2 vlo; vlo.x = cvt_pk_bf16(l0, l1); vlo.y = cvt_pk_bf16(l2, l3);
      *(uint2*)&hBhi[nxt][c][uA0] = vhi;
      *(uint2*)&hBlo[nxt][c][uA0] = vlo;
    }
    if (vB){
      const unsigned int px = cvt_pk_bf16(hnB[0], hnB[1]);
      const unsigned int py = cvt_pk_bf16(hnB[2], hnB[3]);
      const float l0 = hnB[0] - __uint_as_float(px << 16);
      const float l1 = hnB[1] - __uint_as_float(px & 0xFFFF0000u);
      const float l2 = hnB[2] - __uint_as_float(py << 16);
      const float l3 = hnB[3] - __uint_as_float(py & 0xFFFF0000u);
      uint2 vhi; vhi.x = px; vhi.y = py;
      uint2 vlo; vlo.x = cvt_pk_bf16(l0, l1); vlo.y = cvt_pk_bf16(l2, l3);
      *(uint2*)&hBhi[nxt][c][uB0] = vhi;
      *(uint2*)&hBlo[nxt][c][uB0] = vlo;
    }

    if ((s & 3) == 3){
      if (vA){ pA[0]=hnA[0]; pA[4]=hnA[1]; pA[8]=hnA[2]; pA[12]=hnA[3]; pA += CSSTRIDE; }
      if (vB){ pB[0]=hnB[0]; pB[4]=hnB[1]; pB[8]=hnB[2]; pB[12]=hnB[3]; pB += CSSTRIDE; }
    }
    if (s == 511){
      if (vA) *(f32x4*)&out[(size_t)ch*400 + obase + uA0] = hnA;
      if (vB) *(f32x4*)&out[(size_t)ch*400 + obase + uB0] = hnB;
    }
    fast_barrier();   // lgkmcnt(0) only — global stores stay in flight
  }
}

// ---------------------------------------------------------------------------
// L2: I=100, H=50, 128 steps, lane-3 chains, 4 chains/block, 512 blocks.
// (unchanged — verified correct)
// ---------------------------------------------------------------------------
__global__ __launch_bounds__(512, 4)
void gru_l2(const float* __restrict__ x1f, const float* __restrict__ x1b,
            const float* __restrict__ wih_f, const float* __restrict__ whh_f,
            const float* __restrict__ bih_f, const float* __restrict__ bhh_f,
            const float* __restrict__ wih_b, const float* __restrict__ whh_b,
            const float* __restrict__ bih_b, const float* __restrict__ bhh_b,
            float* __restrict__ x2f, float* __restrict__ x2b,
            float* __restrict__ out)
{
  const int dir = (int)(blockIdx.x >> 8);
  const int blk = (int)(blockIdx.x & 255);
  const int t   = (int)threadIdx.x;
  const float* __restrict__ wih = dir ? wih_b : wih_f;
  const float* __restrict__ whh = dir ? whh_b : whh_f;
  const float* __restrict__ bih = dir ? bih_b : bih_f;
  const float* __restrict__ bhh = dir ? bhh_b : bhh_f;
  const float* __restrict__ x1 = dir ? x1b : x1f;
  float* __restrict__ x2 = dir ? x2b : x2f;
  const int obase = dir ? 300 : 100;
  const int b0 = blk * 4;

  __shared__ __align__(16) float xh[2][152][4];

  const int oct = t >> 3;
  const int u   = (oct > 49) ? 49 : oct;
  const int l   = t & 7;
  const int cb  = 19 * l;           // combined col base (0..133)
  float4 W0,W1,W2,W3,W4,W5,W6,W7,W8,W9,W10,W11,W12,W13,W14,W15,W16,W17,W18;
  #define L2LW(J, V) { const int g = cb + (J); \
    const float wr_ = (g<100) ? wih[(size_t)(u     )*100+g] : ((g<150)? whh[(size_t)(u     )*50+g-100] : 0.f); \
    const float wz_ = (g<100) ? wih[(size_t)(u + 50)*100+g] : ((g<150)? whh[(size_t)(u + 50)*50+g-100] : 0.f); \
    const float wx_ = (g<100) ? wih[(size_t)(u +100)*100+g] : 0.f; \
    const float wh_ = (g>=100 && g<150) ? whh[(size_t)(u +100)*50+g-100] : 0.f; \
    V = make_float4(wr_, wz_, wx_, wh_); }
  L2LW(0,W0)  L2LW(1,W1)  L2LW(2,W2)  L2LW(3,W3)  L2LW(4,W4)  L2LW(5,W5)  L2LW(6,W6)
  L2LW(7,W7)  L2LW(8,W8)  L2LW(9,W9)  L2LW(10,W10) L2LW(11,W11) L2LW(12,W12) L2LW(13,W13)
  L2LW(14,W14) L2LW(15,W15) L2LW(16,W16) L2LW(17,W17) L2LW(18,W18)
  #undef L2LW
  const float bcr = bih[u] + bhh[u];
  const float bcz = bih[u+50] + bhh[u+50];
  const float bxn = bih[u+100];
  const float bhn = bhh[u+100];

  for (int i = t; i < 104; i += 512){            // zero h rows + pads, both buffers
    const int bi = (i >= 52) ? 1 : 0;
    const int row = 100 + (i - bi*52);
    *(float4*)&xh[bi][row][0] = make_float4(0.f,0.f,0.f,0.f);
  }
  if (t < 100)                                    // stage x for step 0
    *(float4*)&xh[0][t][0] = *(const float4*)(x1 + (((size_t)0*256 + blk)*100 + t)*4);
  __syncthreads();

  #pragma unroll 1
  for (int s = 0; s < 128; ++s){
    const int cur = s & 1, nxt = cur ^ 1;
    if (t < 400){
      const float* hb = &xh[cur][cb][0];
      float ar0=0,ar1=0,ar2=0,ar3=0, az0=0,az1=0,az2=0,az3=0;
      float ax0=0,ax1=0,ax2=0,ax3=0, ah0=0,ah1=0,ah2=0,ah3=0;
      #define L2C(J, WV) { const float4 h4 = *(const float4*)(hb + 4*(J)); \
        ar0=fmaf(WV.x,h4.x,ar0); ar1=fmaf(WV.x,h4.y,ar1); ar2=fmaf(WV.x,h4.z,ar2); ar3=fmaf(WV.x,h4.w,ar3); \
        az0=fmaf(WV.y,h4.x,az0); az1=fmaf(WV.y,h4.y,az1); az2=fmaf(WV.y,h4.z,az2); az3=fmaf(WV.y,h4.w,az3); \
        ax0=fmaf(WV.z,h4.x,ax0); ax1=fmaf(WV.z,h4.y,ax1); ax2=fmaf(WV.z,h4.z,ax2); ax3=fmaf(WV.z,h4.w,ax3); \
        ah0=fmaf(WV.w,h4.x,ah0); ah1=fmaf(WV.w,h4.y,ah1); ah2=fmaf(WV.w,h4.z,ah2); ah3=fmaf(WV.w,h4.w,ah3); }
      L2C(0,W0)  L2C(1,W1)  L2C(2,W2)  L2C(3,W3)  L2C(4,W4)  L2C(5,W5)  L2C(6,W6)
      L2C(7,W7)  L2C(8,W8)  L2C(9,W9)  L2C(10,W10) L2C(11,W11) L2C(12,W12) L2C(13,W13)
      L2C(14,W14) L2C(15,W15) L2C(16,W16) L2C(17,W17) L2C(18,W18)
      #undef L2C
      ar0=qsum(ar0); ar1=qsum(ar1); ar2=qsum(ar2); ar3=qsum(ar3);
      az0=qsum(az0); az1=qsum(az1); az2=qsum(az2); az3=qsum(az3);
      ax0=qsum(ax0); ax1=qsum(ax1); ax2=qsum(ax2); ax3=qsum(ax3);
      ah0=qsum(ah0); ah1=qsum(ah1); ah2=qsum(ah2); ah3=qsum(ah3);
      ar0=rsum4(ar0); ar1=rsum4(ar1); ar2=rsum4(ar2); ar3=rsum4(ar3);
      az0=rsum4(az0); az1=rsum4(az1); az2=rsum4(az2); az3=rsum4(az3);
      ax0=rsum4(ax0); ax1=rsum4(ax1); ax2=rsum4(ax2); ax3=rsum4(ax3);
      ah0=rsum4(ah0); ah1=rsum4(ah1); ah2=rsum4(ah2); ah3=rsum4(ah3);
      if (l < 4){
        const float Ar = sel4(l, make_float4(ar0,ar1,ar2,ar3));
        const float Az = sel4(l, make_float4(az0,az1,az2,az3));
        const float Ax = sel4(l, make_float4(ax0,ax1,ax2,ax3));
        const float Ah = sel4(l, make_float4(ah0,ah1,ah2,ah3));
        const float ho = xh[cur][100+u][l];
        const float r = sigf(Ar + bcr);
        const float z = sigf(Az + bcz);
        const float n = tanhf_fast(Ax + bxn + r*(Ah + bhn));
        const float hnew = n + z*(ho - n);
        xh[nxt][100+u][l] = hnew;
        if ((s & 3) == 3) x2[(((size_t)(s>>2)*256 + blk)*50 + u)*4 + l] = hnew;
        if (s == 127)     out[(size_t)(b0 + l)*400 + obase + u] = hnew;
      }
    } else if (t < 500){
      if (s + 1 < 128){
        const int j = t - 400;
        *(float4*)&xh[nxt][j][0] = *(const float4*)(x1 + (((size_t)(s+1)*256 + blk)*100 + j)*4);
      }
    }
    __syncthreads();
  }
}

// ---------------------------------------------------------------------------
// L3: I=50, H=50, 32 steps, lane-15 chains. (unchanged — verified correct)
// ---------------------------------------------------------------------------
__global__ __launch_bounds__(512, 4)
void gru_l3(const float* __restrict__ x2f, const float* __restrict__ x2b,
            const float* __restrict__ wih_f, const float* __restrict__ whh_f,
            const float* __restrict__ bih_f, const float* __restrict__ bhh_f,
            const float* __restrict__ wih_b, const float* __restrict__ whh_b,
            const float* __restrict__ bih_b, const float* __restrict__ bhh_b,
            float* __restrict__ out)
{
  const int dir = (int)(blockIdx.x >> 8);
  const int blk = (int)(blockIdx.x & 255);
  const int t   = (int)threadIdx.x;
  const float* __restrict__ wih = dir ? wih_b : wih_f;
  const float* __restrict__ whh = dir ? whh_b : whh_f;
  const float* __restrict__ bih = dir ? bih_b : bih_f;
  const float* __restrict__ bhh = dir ? bhh_b : bhh_f;
  const float* __restrict__ x2 = dir ? x2b : x2f;
  const int obase = dir ? 350 : 150;
  const int b0 = blk * 4;

  __shared__ __align__(16) float xh[2][104][4];

  const int oct = t >> 3;
  const int u   = (oct > 49) ? 49 : oct;
  const int l   = t & 7;
  const int cb  = 13 * l;           // 0..91
  float4 W0,W1,W2,W3,W4,W5,W6,W7,W8,W9,W10,W11,W12;
  #define L3LW(J, V) { const int g = cb + (J); \
    const float wr_ = (g<50) ? wih[(size_t)(u     )*50+g] : ((g<100)? whh[(size_t)(u     )*50+g-50] : 0.f); \
    const float wz_ = (g<50) ? wih[(size_t)(u + 50)*50+g] : ((g<100)? whh[(size_t)(u + 50)*50+g-50] : 0.f); \
    const float wx_ = (g<50) ? wih[(size_t)(u +100)*50+g] : 0.f; \
    const float wh_ = (g>=50 && g<100) ? whh[(size_t)(u +100)*50+g-50] : 0.f; \
    V = make_float4(wr_, wz_, wx_, wh_); }
  L3LW(0,W0) L3LW(1,W1) L3LW(2,W2) L3LW(3,W3) L3LW(4,W4) L3LW(5,W5) L3LW(6,W6)
  L3LW(7,W7) L3LW(8,W8) L3LW(9,W9) L3LW(10,W10) L3LW(11,W11) L3LW(12,W12)
  #undef L3LW
  const float bcr = bih[u] + bhh[u];
  const float bcz = bih[u+50] + bhh[u+50];
  const float bxn = bih[u+100];
  const float bhn = bhh[u+100];

  for (int i = t; i < 108; i += 512){            // zero h rows + pads, both buffers
    const int bi = (i >= 54) ? 1 : 0;
    const int row = 50 + (i - bi*54);
    *(float4*)&xh[bi][row][0] = make_float4(0.f,0.f,0.f,0.f);
  }
  if (t < 50)
    *(float4*)&xh[0][t][0] = *(const float4*)(x2 + (((size_t)0*256 + blk)*50 + t)*4);
  __syncthreads();

  #pragma unroll 1
  for (int s = 0; s < 32; ++s){
    const int cur = s & 1, nxt = cur ^ 1;
    if (t < 400){
      const float* hb = &xh[cur][cb][0];
      float ar0=0,ar1=0,ar2=0,ar3=0, az0=0,az1=0,az2=0,az3=0;
      float ax0=0,ax1=0,ax2=0,ax3=0, ah0=0,ah1=0,ah2=0,ah3=0;
      #define L3C(J, WV) { const float4 h4 = *(const float4*)(hb + 4*(J)); \
        ar0=fmaf(WV.x,h4.x,ar0); ar1=fmaf(WV.x,h4.y,ar1); ar2=fmaf(WV.x,h4.z,ar2); ar3=fmaf(WV.x,h4.w,ar3); \
        az0=fmaf(WV.y,h4.x,az0); az1=fmaf(WV.y,h4.y,az1); az2=fmaf(WV.y,h4.z,az2); az3=fmaf(WV.y,h4.w,az3); \
        ax0=fmaf(WV.z,h4.x,ax0); ax1=fmaf(WV.z,h4.y,ax1); ax2=fmaf(WV.z,h4.z,ax2); ax3=fmaf(WV.z,h4.w,ax3); \
        ah0=fmaf(WV.w,h4.x,ah0); ah1=fmaf(WV.w,h4.y,ah1); ah2=fmaf(WV.w,h4.z,ah2); ah3=fmaf(WV.w,h4.w,ah3); }
      L3C(0,W0) L3C(1,W1) L3C(2,W2) L3C(3,W3) L3C(4,W4) L3C(5,W5) L3C(6,W6)
      L3C(7,W7) L3C(8,W8) L3C(9,W9) L3C(10,W10) L3C(11,W11) L3C(12,W12)
      #undef L3C
      ar0=qsum(ar0); ar1=qsum(ar1); ar2=qsum(ar2); ar3=qsum(ar3);
      az0=qsum(az0); az1=qsum(az1); az2=qsum(az2); az3=qsum(az3);
      ax0=qsum(ax0); ax1=qsum(ax1); ax2=qsum(ax2); ax3=qsum(ax3);
      ah0=qsum(ah0); ah1=qsum(ah1); ah2=qsum(ah2); ah3=qsum(ah3);
      ar0=rsum4(ar0); ar1=rsum4(ar1); ar2=rsum4(ar2); ar3=rsum4(ar3);
      az0=rsum4(az0); az1=rsum4(az1); az2=rsum4(az2); az3=rsum4(az3);
      ax0=rsum4(ax0); ax1=rsum4(ax1); ax2=rsum4(ax2); ax3=rsum4(ax3);
      ah0=rsum4(ah0); ah1=rsum4(ah1); ah2=rsum4(ah2); ah3=rsum4(ah3);
      if (l < 4){
        const float Ar = sel4(l, make_float4(ar0,ar1,ar2,ar3));
        const float Az = sel4(l, make_float4(az0,az1,az2,az3));
        const float Ax = sel4(l, make_float4(ax0,ax1,ax2,ax3));
        const float Ah = sel4(l, make_float4(ah0,ah1,ah2,ah3));
        const float ho = xh[cur][50+u][l];
        const float r = sigf(Ar + bcr);
        const float z = sigf(Az + bcz);
        const float n = tanhf_fast(Ax + bxn + r*(Ah + bhn));
        const float hnew = n + z*(ho - n);
        xh[nxt][50+u][l] = hnew;
        if (s == 31) out[(size_t)(b0 + l)*400 + obase + u] = hnew;
      }
    } else if (t < 450){
      if (s + 1 < 32){
        const int j = t - 400;
        *(float4*)&xh[nxt][j][0] = *(const float4*)(x2 + (((size_t)(s+1)*256 + blk)*50 + j)*4);
      }
    }
    __syncthreads();
  }
}

extern "C" void kernel_launch(void* const* d_in, const int* in_sizes, int n_in,
                              void* d_out, int out_size, void* d_ws, size_t ws_size,
                              hipStream_t stream)
{
  const float* data   = (const float*)d_in[0];
  const float* f1_wih = (const float*)d_in[1];
  const float* f1_whh = (const float*)d_in[2];
  const float* f1_bih = (const float*)d_in[3];
  const float* f1_bhh = (const float*)d_in[4];
  const float* f2_wih = (const float*)d_in[5];
  const float* f2_whh = (const float*)d_in[6];
  const float* f2_bih = (const float*)d_in[7];
  const float* f2_bhh = (const float*)d_in[8];
  const float* f3_wih = (const float*)d_in[9];
  const float* f3_whh = (const float*)d_in[10];
  const float* f3_bih = (const float*)d_in[11];
  const float* f3_bhh = (const float*)d_in[12];
  const float* b1_wih = (const float*)d_in[13];
  const float* b1_whh = (const float*)d_in[14];
  const float* b1_bih = (const float*)d_in[15];
  const float* b1_bhh = (const float*)d_in[16];
  const float* b2_wih = (const float*)d_in[17];
  const float* b2_whh = (const float*)d_in[18];
  const float* b2_bih = (const float*)d_in[19];
  const float* b2_bhh = (const float*)d_in[20];
  const float* b3_wih = (const float*)d_in[21];
  const float* b3_whh = (const float*)d_in[22];
  const float* b3_bih = (const float*)d_in[23];
  const float* b3_bhh = (const float*)d_in[24];
  float* out = (float*)d_out;

  const size_t X1N = (size_t)128 * 256 * 100 * 4;  // [cs][blk][unit][chain]
  const size_t X2N = (size_t)32 * 256 * 50 * 4;    // [k2][blk][unit][chain]
  if (ws_size < (2 * X1N + 2 * X2N) * sizeof(float)) return;
  float* wsf = (float*)d_ws;
  float* x1f = wsf;
  float* x1b = wsf + X1N;
  float* x2f = wsf + 2 * X1N;
  float* x2b = wsf + 2 * X1N + X2N;

  gru_l1<<<dim3(128), dim3(256), 0, stream>>>(
      data, f1_wih, f1_whh, f1_bih, f1_bhh,
      b1_wih, b1_whh, b1_bih, b1_bhh, x1f, x1b, out);
  gru_l2<<<dim3(512), dim3(512), 0, stream>>>(
      x1f, x1b, f2_wih, f2_whh, f2_bih, f2_bhh,
      b2_wih, b2_whh, b2_bih, b2_bhh, x2f, x2b, out);
  gru_l3<<<dim3(512), dim3(512), 0, stream>>>(
      x2f, x2b, f3_wih, f3_whh, f3_bih, f3_bhh,
      b3_wih, b3_whh, b3_bih, b3_bhh, out);
}

// Round 11
// 1023.557 us; speedup vs baseline: 1.1945x; 1.1898x over previous
//
#include <hip/hip_runtime.h>
#include <math.h>

typedef short  s16x8 __attribute__((ext_vector_type(8)));   // 8 bf16 bit-patterns (4 VGPRs)
typedef float  f32x4 __attribute__((ext_vector_type(4)));

static __device__ __forceinline__ float sigf(float x){ return 1.0f/(1.0f+__expf(-x)); }
static __device__ __forceinline__ float tanhf_fast(float x){
  float ax=fabsf(x); float e=__expf(-2.0f*ax); float t=(1.0f-e)/(1.0f+e); return copysignf(t,x);
}
static __device__ __forceinline__ unsigned short f2bf(float x){  // RNE f32->bf16 bits (A-frag prep)
  unsigned int u = __float_as_uint(x);
  unsigned int r = (u + 0x7FFFu + ((u >> 16) & 1u)) >> 16;
  return (unsigned short)r;
}
static __device__ __forceinline__ float bf2f(unsigned short b){
  return __uint_as_float(((unsigned int)b) << 16);
}
// packed f32x2 -> bf16x2; lo term computed from ACTUAL hi bits => split self-corrects.
static __device__ __forceinline__ unsigned int cvt_pk_bf16(float a, float b){
  unsigned int r;
  asm("v_cvt_pk_bf16_f32 %0, %1, %2" : "=v"(r) : "v"(a), "v"(b));
  return r;
}
// barrier without vmcnt drain: LDS writes ordered, global stores stay in flight.
static __device__ __forceinline__ void fast_barrier(){
  asm volatile("s_waitcnt lgkmcnt(0)" ::: "memory");
  __builtin_amdgcn_s_barrier();
}
// quad/octet reduce helpers (verified r4) — used by L3
static __device__ __forceinline__ float qsum(float v){
  v += __int_as_float(__builtin_amdgcn_mov_dpp(__float_as_int(v),0xB1,0xF,0xF,true));
  v += __int_as_float(__builtin_amdgcn_mov_dpp(__float_as_int(v),0x4E,0xF,0xF,true));
  return v;
}
static __device__ __forceinline__ float rsum4(float v){
  return v + __int_as_float(__builtin_amdgcn_ds_swizzle(__float_as_int(v), 0x101F));
}
static __device__ __forceinline__ float sel4(int c, float4 v){
  float r=v.x; r=(c==1)?v.y:r; r=(c==2)?v.z:r; r=(c==3)?v.w:r; return r;
}

// L1 A-fragment pair (hi/lo split), per-gate tiling: rows tile*16..+15 of gate.
// mfma_f32_16x16x32_bf16 A layout: lane l holds A[m=l&15][k=(l>>4)*8+j].
static __device__ __forceinline__ void load_afrag(const float* __restrict__ whh,
                                                  int gate, int tile, int l, int kc,
                                                  s16x8& hi, s16x8& lo){
  const int r  = tile*16 + (l & 15);
  const int kb = kc*32 + (l >> 4)*8;
  #pragma unroll
  for (int j = 0; j < 8; ++j){
    const int k = kb + j;
    const float wv = (r < 100 && k < 100) ? whh[(size_t)(gate*100 + r)*100 + k] : 0.0f;
    const unsigned short hb = f2bf(wv);
    hi[j] = (short)hb;
    lo[j] = (short)f2bf(wv - bf2f(hb));
  }
}

// ---------------------------------------------------------------------------
// L1 (MFMA, 7 waves, fused finalize) — the round-8-verified 848us kernel,
// with fast_barrier instead of __syncthreads in the step loop.
// ---------------------------------------------------------------------------
__global__ __launch_bounds__(448, 2)
void gru_l1(const float* __restrict__ data,
            const float* __restrict__ wih_f, const float* __restrict__ whh_f,
            const float* __restrict__ bih_f, const float* __restrict__ bhh_f,
            const float* __restrict__ wih_b, const float* __restrict__ whh_b,
            const float* __restrict__ bih_b, const float* __restrict__ bhh_b,
            float* __restrict__ x1f, float* __restrict__ x1b,
            float* __restrict__ out)
{
  const int dir   = (int)(blockIdx.x >> 6);
  const int blk16 = (int)(blockIdx.x & 63);
  const int t     = (int)threadIdx.x;
  const float* __restrict__ wih = dir ? wih_b : wih_f;
  const float* __restrict__ whh = dir ? whh_b : whh_f;
  const float* __restrict__ bih = dir ? bih_b : bih_f;
  const float* __restrict__ bhh = dir ? bhh_b : bhh_f;
  float* __restrict__ x1 = dir ? x1b : x1f;
  const int obase = dir ? 200 : 0;
  const int b0 = blk16 * 16;

  __shared__ __align__(16) unsigned short hBhi[2][16][136]; // [buf][chain][k]
  __shared__ __align__(16) unsigned short hBlo[2][16][136];
  __shared__ __align__(16) float xs[512][16];               // [step][chain], dir-adjusted

  for (int i = t; i < 8192; i += 448){
    const int c  = i >> 9;
    const int sL = i & 511;
    xs[sL][c] = data[(size_t)(b0 + c)*512 + (size_t)(dir ? (511 - sL) : sL)];
  }
  { unsigned short* ph = (unsigned short*)hBhi;
    unsigned short* pl = (unsigned short*)hBlo;
    for (int i = t; i < 2*16*136; i += 448){ ph[i] = 0; pl[i] = 0; } }

  const int l  = t & 63;
  const int W  = t >> 6;   // wave = row-tile ti (0..6)

  // A-fragments: 3 gates x 4 kc x (hi,lo)
  s16x8 AH00,AH01,AH02,AH03, AH10,AH11,AH12,AH13, AH20,AH21,AH22,AH23;
  s16x8 AL00,AL01,AL02,AL03, AL10,AL11,AL12,AL13, AL20,AL21,AL22,AL23;
  #define LDA(G,KC) load_afrag(whh, G, W, l, KC, AH##G##KC, AL##G##KC);
  LDA(0,0) LDA(0,1) LDA(0,2) LDA(0,3)
  LDA(1,0) LDA(1,1) LDA(1,2) LDA(1,3)
  LDA(2,0) LDA(2,1) LDA(2,2) LDA(2,3)
  #undef LDA

  const int mg  = (l >> 4) * 4;
  const int u0  = W*16 + mg;                 // 0..124
  const bool uvalid = (u0 < 100);
  const int u0c = uvalid ? u0 : 96;
  const int c   = l & 15;
  const f32x4 wxr4 = *(const f32x4*)&wih[u0c];
  const f32x4 wxz4 = *(const f32x4*)&wih[100 + u0c];
  const f32x4 wxn4 = *(const f32x4*)&wih[200 + u0c];
  const f32x4 bcr4 = *(const f32x4*)&bih[u0c]       + *(const f32x4*)&bhh[u0c];
  const f32x4 bcz4 = *(const f32x4*)&bih[100 + u0c] + *(const f32x4*)&bhh[100 + u0c];
  const f32x4 bxn4 = *(const f32x4*)&bih[200 + u0c];
  const f32x4 bhn4 = *(const f32x4*)&bhh[200 + u0c];
  f32x4 hprev = {0.f,0.f,0.f,0.f};

  __syncthreads();

  const int bn = c;
  const int bg = (l >> 4)*8;

  #pragma unroll 1
  for (int s = 0; s < 512; ++s){
    const int cur = s & 1, nxt = cur ^ 1;

    const s16x8 BH0 = *(const s16x8*)&hBhi[cur][bn][ 0 + bg];
    const s16x8 BL0 = *(const s16x8*)&hBlo[cur][bn][ 0 + bg];
    const s16x8 BH1 = *(const s16x8*)&hBhi[cur][bn][32 + bg];
    const s16x8 BL1 = *(const s16x8*)&hBlo[cur][bn][32 + bg];
    const s16x8 BH2 = *(const s16x8*)&hBhi[cur][bn][64 + bg];
    const s16x8 BL2 = *(const s16x8*)&hBlo[cur][bn][64 + bg];
    const s16x8 BH3 = *(const s16x8*)&hBhi[cur][bn][96 + bg];
    const s16x8 BL3 = *(const s16x8*)&hBlo[cur][bn][96 + bg];

    f32x4 Ca0={0.f,0.f,0.f,0.f}, Cb0={0.f,0.f,0.f,0.f};
    f32x4 Ca1={0.f,0.f,0.f,0.f}, Cb1={0.f,0.f,0.f,0.f};
    f32x4 Ca2={0.f,0.f,0.f,0.f}, Cb2={0.f,0.f,0.f,0.f};
    #define MM(ACC,G,KC) \
      ACC = __builtin_amdgcn_mfma_f32_16x16x32_bf16(AL##G##KC, BH##KC, ACC, 0, 0, 0); \
      ACC = __builtin_amdgcn_mfma_f32_16x16x32_bf16(AH##G##KC, BL##KC, ACC, 0, 0, 0); \
      ACC = __builtin_amdgcn_mfma_f32_16x16x32_bf16(AH##G##KC, BH##KC, ACC, 0, 0, 0);
    MM(Ca0,0,0) MM(Ca1,1,0) MM(Ca2,2,0)
    MM(Cb0,0,2) MM(Cb1,1,2) MM(Cb2,2,2)
    MM(Ca0,0,1) MM(Ca1,1,1) MM(Ca2,2,1)
    MM(Cb0,0,3) MM(Cb1,1,3) MM(Cb2,2,3)
    #undef MM
    const f32x4 sr = Ca0 + Cb0;
    const f32x4 sz = Ca1 + Cb1;
    const f32x4 sn = Ca2 + Cb2;

    const float xc = xs[s][c];
    f32x4 hn;
    #define FIN(I) { \
      const float rr = sigf(sr[I] + fmaf(wxr4[I], xc, bcr4[I])); \
      const float zz = sigf(sz[I] + fmaf(wxz4[I], xc, bcz4[I])); \
      const float nn = tanhf_fast(fmaf(wxn4[I], xc, bxn4[I]) + rr*(sn[I] + bhn4[I])); \
      hn[I] = nn + zz*(hprev[I] - nn); }
    FIN(0) FIN(1) FIN(2) FIN(3)
    #undef FIN
    hprev = hn;

    if (uvalid){
      const unsigned int px = cvt_pk_bf16(hn[0], hn[1]);
      const unsigned int py = cvt_pk_bf16(hn[2], hn[3]);
      const float l0 = hn[0] - __uint_as_float(px << 16);
      const float l1 = hn[1] - __uint_as_float(px & 0xFFFF0000u);
      const float l2 = hn[2] - __uint_as_float(py << 16);
      const float l3 = hn[3] - __uint_as_float(py & 0xFFFF0000u);
      uint2 vhi; vhi.x = px; vhi.y = py;
      uint2 vlo; vlo.x = cvt_pk_bf16(l0, l1); vlo.y = cvt_pk_bf16(l2, l3);
      *(uint2*)&hBhi[nxt][c][u0] = vhi;
      *(uint2*)&hBlo[nxt][c][u0] = vlo;
      if ((s & 3) == 3){
        const int cs = s >> 2;
        const int ch = b0 + c;
        const size_t base = (((size_t)cs*256 + (ch >> 2))*100);
        x1[(base + u0 + 0)*4 + (ch & 3)] = hn[0];
        x1[(base + u0 + 1)*4 + (ch & 3)] = hn[1];
        x1[(base + u0 + 2)*4 + (ch & 3)] = hn[2];
        x1[(base + u0 + 3)*4 + (ch & 3)] = hn[3];
      }
      if (s == 511){
        const int ch = b0 + c;
        *(f32x4*)&out[(size_t)ch*400 + obase + u0] = hn;
      }
    }
    fast_barrier();
  }
}

// L2 A-matrix value: 4 sections x 64 rows x 160 cols.
// sec 0: r-combined [wih_r | pad | whh_r | pad], sec 1: z-combined,
// sec 2: n-x [wih_n | 0], sec 3: n-h [0 | whh_n | 0].
// k map: x at k in [0,100), h at k in [104,154), zeros elsewhere.
static __device__ __forceinline__ float l2w(const float* __restrict__ wih,
                                            const float* __restrict__ whh,
                                            int sec, int r, int k){
  if (r >= 50) return 0.f;
  if (sec == 2) return (k < 100) ? wih[(size_t)(100 + r)*100 + k] : 0.f;
  if (sec == 3) return (k >= 104 && k < 154) ? whh[(size_t)(100 + r)*50 + (k - 104)] : 0.f;
  const int ro = (sec == 1) ? 50 : 0;
  if (k < 100) return wih[(size_t)(ro + r)*100 + k];
  if (k >= 104 && k < 154) return whh[(size_t)(ro + r)*50 + (k - 104)];
  return 0.f;
}
static __device__ __forceinline__ void l2_afrag(const float* __restrict__ wih,
                                                const float* __restrict__ whh,
                                                int sec, int tile, int l, int kc,
                                                s16x8& hi, s16x8& lo){
  const int r  = tile*16 + (l & 15);
  const int kb = kc*32 + (l >> 4)*8;
  #pragma unroll
  for (int j = 0; j < 8; ++j){
    const float wv = l2w(wih, whh, sec, r, kb + j);
    const unsigned short hb = f2bf(wv);
    hi[j] = (short)hb;
    lo[j] = (short)f2bf(wv - bf2f(hb));
  }
}

// ---------------------------------------------------------------------------
// L2 (MFMA): I=100, H=50, 128 steps, 16 chains/block, 128 blocks (64 fwd +
// 64 bwd), 256 threads = 4 waves. Wave W owns tile W (16 rows) of all 4
// sections -> C frags for r,z,nx,nh of unit u=W*16+(l>>4)*4+reg, chain l&15
// in the same lane => fused lane-local finalize. B=[x|h] bf16 hi/lo in LDS,
// x_{s+1} prefetched (issue-early/write-late). ONE barrier/step.
// ---------------------------------------------------------------------------
__global__ __launch_bounds__(256, 1)
void gru_l2(const float* __restrict__ x1f, const float* __restrict__ x1b,
            const float* __restrict__ wih_f, const float* __restrict__ whh_f,
            const float* __restrict__ bih_f, const float* __restrict__ bhh_f,
            const float* __restrict__ wih_b, const float* __restrict__ whh_b,
            const float* __restrict__ bih_b, const float* __restrict__ bhh_b,
            float* __restrict__ x2f, float* __restrict__ x2b,
            float* __restrict__ out)
{
  const int dir   = (int)(blockIdx.x >> 6);
  const int blk16 = (int)(blockIdx.x & 63);
  const int t     = (int)threadIdx.x;
  const float* __restrict__ wih = dir ? wih_b : wih_f;
  const float* __restrict__ whh = dir ? whh_b : whh_f;
  const float* __restrict__ bih = dir ? bih_b : bih_f;
  const float* __restrict__ bhh = dir ? bhh_b : bhh_f;
  const float* __restrict__ x1 = dir ? x1b : x1f;
  float* __restrict__ x2 = dir ? x2b : x2f;
  const int obase = dir ? 300 : 100;
  const int b0 = blk16 * 16;

  __shared__ __align__(16) unsigned short hBhi[2][16][168]; // [buf][chain][k] (K pad 160->168)
  __shared__ __align__(16) unsigned short hBlo[2][16][168];

  { unsigned short* ph = (unsigned short*)hBhi;
    unsigned short* pl = (unsigned short*)hBlo;
    for (int i = t; i < 2*16*168; i += 256){ ph[i] = 0; pl[i] = 0; } }

  const int l = t & 63;
  const int W = t >> 6;   // wave 0..3 = tile index

  // A-fragments: 4 sections x 5 kc x (hi,lo) = 40 frags
  s16x8 AH00,AH01,AH02,AH03,AH04, AH10,AH11,AH12,AH13,AH14,
        AH20,AH21,AH22,AH23,AH24, AH30,AH31,AH32,AH33,AH34;
  s16x8 AL00,AL01,AL02,AL03,AL04, AL10,AL11,AL12,AL13,AL14,
        AL20,AL21,AL22,AL23,AL24, AL30,AL31,AL32,AL33,AL34;
  #define LDA(SE,KC) l2_afrag(wih, whh, SE, W, l, KC, AH##SE##KC, AL##SE##KC);
  LDA(0,0) LDA(0,1) LDA(0,2) LDA(0,3) LDA(0,4)
  LDA(1,0) LDA(1,1) LDA(1,2) LDA(1,3) LDA(1,4)
  LDA(2,0) LDA(2,1) LDA(2,2) LDA(2,3) LDA(2,4)
  LDA(3,0) LDA(3,1) LDA(3,2) LDA(3,3) LDA(3,4)
  #undef LDA

  // per-lane finalize constants (element-clamped)
  const int mg = (l >> 4) * 4;
  const int c  = l & 15;
  const int u0 = W*16 + mg;                 // 0..60
  const int ch = b0 + c;
  f32x4 bcr, bcz, bxn, bhn;
  #pragma unroll
  for (int i = 0; i < 4; ++i){
    const int u = (u0 + i < 50) ? (u0 + i) : 49;
    bcr[i] = bih[u]      + bhh[u];
    bcz[i] = bih[50 + u] + bhh[50 + u];
    bxn[i] = bih[100 + u];
    bhn[i] = bhh[100 + u];
  }
  const bool vH = (u0 < 50);
  f32x4 hp = {0.f,0.f,0.f,0.f};

  // x2 incremental store base (layout preserved for L3)
  float* px = x2 + (((size_t)(ch >> 2))*50 + u0)*4 + (ch & 3);
  const size_t X2STRIDE = (size_t)256*50*4;

  // stage roles: t<208 -> oct (unit octet), cc (chain)
  const int oct  = t >> 4;        // 0..15 (use <13)
  const int cc   = t & 15;
  const bool stg = (t < 208);
  const int u0x  = oct * 8;

  __syncthreads();

  // pre-stage x_0 into buffer 0
  if (stg){
    const float* p = x1 + ((size_t)0*256 + (b0 >> 2) + (cc >> 2))*400 + (cc & 3);
    float xv[8];
    #pragma unroll
    for (int j = 0; j < 8; ++j){
      const int uu = u0x + j;
      xv[j] = (uu < 100) ? p[4*uu] : 0.f;
    }
    unsigned int h0 = cvt_pk_bf16(xv[0], xv[1]);
    unsigned int h1 = cvt_pk_bf16(xv[2], xv[3]);
    unsigned int h2 = cvt_pk_bf16(xv[4], xv[5]);
    unsigned int h3 = cvt_pk_bf16(xv[6], xv[7]);
    uint4 vhi; vhi.x=h0; vhi.y=h1; vhi.z=h2; vhi.w=h3;
    uint4 vlo;
    vlo.x = cvt_pk_bf16(xv[0]-__uint_as_float(h0<<16), xv[1]-__uint_as_float(h0&0xFFFF0000u));
    vlo.y = cvt_pk_bf16(xv[2]-__uint_as_float(h1<<16), xv[3]-__uint_as_float(h1&0xFFFF0000u));
    vlo.z = cvt_pk_bf16(xv[4]-__uint_as_float(h2<<16), xv[5]-__uint_as_float(h2&0xFFFF0000u));
    vlo.w = cvt_pk_bf16(xv[6]-__uint_as_float(h3<<16), xv[7]-__uint_as_float(h3&0xFFFF0000u));
    *(uint4*)&hBhi[0][cc][u0x] = vhi;
    *(uint4*)&hBlo[0][cc][u0x] = vlo;
  }
  __syncthreads();

  const int bn = c;
  const int bg = (l >> 4)*8;

  #pragma unroll 1
  for (int s = 0; s < 128; ++s){
    const int cur = s & 1, nxt = cur ^ 1;

    // issue next-step x loads early (consumed after finalize -> latency hidden)
    float xv0=0,xv1=0,xv2=0,xv3=0,xv4=0,xv5=0,xv6=0,xv7=0;
    if (stg){
      const int st = (s + 1 < 128) ? (s + 1) : 127;
      const float* p = x1 + ((size_t)st*256 + (b0 >> 2) + (cc >> 2))*400 + (cc & 3);
      #define XL(J, V) { const int uu = u0x + (J); \
        V = (uu < 100) ? p[4*uu] : 0.f; }
      XL(0,xv0) XL(1,xv1) XL(2,xv2) XL(3,xv3) XL(4,xv4) XL(5,xv5) XL(6,xv6) XL(7,xv7)
      #undef XL
    }

    // B fragments (x|h, bf16 hi/lo): 5 kc
    const s16x8 BH0 = *(const s16x8*)&hBhi[cur][bn][  0 + bg];
    const s16x8 BL0 = *(const s16x8*)&hBlo[cur][bn][  0 + bg];
    const s16x8 BH1 = *(const s16x8*)&hBhi[cur][bn][ 32 + bg];
    const s16x8 BL1 = *(const s16x8*)&hBlo[cur][bn][ 32 + bg];
    const s16x8 BH2 = *(const s16x8*)&hBhi[cur][bn][ 64 + bg];
    const s16x8 BL2 = *(const s16x8*)&hBlo[cur][bn][ 64 + bg];
    const s16x8 BH3 = *(const s16x8*)&hBhi[cur][bn][ 96 + bg];
    const s16x8 BL3 = *(const s16x8*)&hBlo[cur][bn][ 96 + bg];
    const s16x8 BH4 = *(const s16x8*)&hBhi[cur][bn][128 + bg];
    const s16x8 BL4 = *(const s16x8*)&hBlo[cur][bn][128 + bg];

    // MFMA: 8 acc groups (A: kc 0,1,2 / B: kc 3,4), alternating -> dep dist 8
    f32x4 CrA={0.f,0.f,0.f,0.f}, CzA={0.f,0.f,0.f,0.f}, CxA={0.f,0.f,0.f,0.f}, ChA={0.f,0.f,0.f,0.f};
    f32x4 CrB={0.f,0.f,0.f,0.f}, CzB={0.f,0.f,0.f,0.f}, CxB={0.f,0.f,0.f,0.f}, ChB={0.f,0.f,0.f,0.f};
    #define MF(ACC,A,B) ACC = __builtin_amdgcn_mfma_f32_16x16x32_bf16(A, B, ACC, 0, 0, 0);
    #define G4(SET,KC,AOP,BOP) \
      MF(Cr##SET, AOP##0##KC, BOP##KC) MF(Cz##SET, AOP##1##KC, BOP##KC) \
      MF(Cx##SET, AOP##2##KC, BOP##KC) MF(Ch##SET, AOP##3##KC, BOP##KC)
    G4(A,0,AL,BH) G4(B,3,AL,BH) G4(A,1,AL,BH) G4(B,4,AL,BH) G4(A,2,AL,BH)
    G4(A,0,AH,BL) G4(B,3,AH,BL) G4(A,1,AH,BL) G4(B,4,AH,BL) G4(A,2,AH,BL)
    G4(A,0,AH,BH) G4(B,3,AH,BH) G4(A,1,AH,BH) G4(B,4,AH,BH) G4(A,2,AH,BH)
    #undef G4
    #undef MF
    const f32x4 Cr = CrA + CrB;
    const f32x4 Cz = CzA + CzB;
    const f32x4 Cx = CxA + CxB;
    const f32x4 Ch = ChA + ChB;

    // fused finalize: 4 cells per lane
    f32x4 hn;
    #define FIN(I) { \
      const float rr = sigf(Cr[I] + bcr[I]); \
      const float zz = sigf(Cz[I] + bcz[I]); \
      const float nn = tanhf_fast(Cx[I] + bxn[I] + rr*(Ch[I] + bhn[I])); \
      hn[I] = nn + zz*(hp[I] - nn); }
    FIN(0) FIN(1) FIN(2) FIN(3)
    #undef FIN
    hp = hn;

    if (vH){
      const unsigned int p0 = cvt_pk_bf16(hn[0], hn[1]);
      const unsigned int p1 = cvt_pk_bf16(hn[2], hn[3]);
      const float l0 = hn[0] - __uint_as_float(p0 << 16);
      const float l1 = hn[1] - __uint_as_float(p0 & 0xFFFF0000u);
      const float l2 = hn[2] - __uint_as_float(p1 << 16);
      const float l3 = hn[3] - __uint_as_float(p1 & 0xFFFF0000u);
      uint2 whi; whi.x = p0; whi.y = p1;
      uint2 wlo; wlo.x = cvt_pk_bf16(l0, l1); wlo.y = cvt_pk_bf16(l2, l3);
      *(uint2*)&hBhi[nxt][c][104 + u0] = whi;
      *(uint2*)&hBlo[nxt][c][104 + u0] = wlo;
      if ((s & 3) == 3){
        if (u0 + 0 < 50) px[ 0] = hn[0];
        if (u0 + 1 < 50) px[ 4] = hn[1];
        if (u0 + 2 < 50) px[ 8] = hn[2];
        if (u0 + 3 < 50) px[12] = hn[3];
        px += X2STRIDE;
      }
      if (s == 127){
        if (u0 + 0 < 50) out[(size_t)ch*400 + obase + u0 + 0] = hn[0];
        if (u0 + 1 < 50) out[(size_t)ch*400 + obase + u0 + 1] = hn[1];
        if (u0 + 2 < 50) out[(size_t)ch*400 + obase + u0 + 2] = hn[2];
        if (u0 + 3 < 50) out[(size_t)ch*400 + obase + u0 + 3] = hn[3];
      }
    }

    // write prefetched x into next buffer (vmcnt waited implicitly at first use)
    if (stg){
      unsigned int h0 = cvt_pk_bf16(xv0, xv1);
      unsigned int h1 = cvt_pk_bf16(xv2, xv3);
      unsigned int h2 = cvt_pk_bf16(xv4, xv5);
      unsigned int h3 = cvt_pk_bf16(xv6, xv7);
      uint4 vhi; vhi.x=h0; vhi.y=h1; vhi.z=h2; vhi.w=h3;
      uint4 vlo;
      vlo.x = cvt_pk_bf16(xv0-__uint_as_float(h0<<16), xv1-__uint_as_float(h0&0xFFFF0000u));
      vlo.y = cvt_pk_bf16(xv2-__uint_as_float(h1<<16), xv3-__uint_as_float(h1&0xFFFF0000u));
      vlo.z = cvt_pk_bf16(xv4-__uint_as_float(h2<<16), xv5-__uint_as_float(h2&0xFFFF0000u));
      vlo.w = cvt_pk_bf16(xv6-__uint_as_float(h3<<16), xv7-__uint_as_float(h3&0xFFFF0000u));
      *(uint4*)&hBhi[nxt][cc][u0x] = vhi;
      *(uint4*)&hBlo[nxt][cc][u0x] = vlo;
    }
    fast_barrier();
  }
}

// ---------------------------------------------------------------------------
// L3: I=50, H=50, 32 steps, lane-15 chains. (unchanged — verified correct)
// ---------------------------------------------------------------------------
__global__ __launch_bounds__(512, 4)
void gru_l3(const float* __restrict__ x2f, const float* __restrict__ x2b,
            const float* __restrict__ wih_f, const float* __restrict__ whh_f,
            const float* __restrict__ bih_f, const float* __restrict__ bhh_f,
            const float* __restrict__ wih_b, const float* __restrict__ whh_b,
            const float* __restrict__ bih_b, const float* __restrict__ bhh_b,
            float* __restrict__ out)
{
  const int dir = (int)(blockIdx.x >> 8);
  const int blk = (int)(blockIdx.x & 255);
  const int t   = (int)threadIdx.x;
  const float* __restrict__ wih = dir ? wih_b : wih_f;
  const float* __restrict__ whh = dir ? whh_b : whh_f;
  const float* __restrict__ bih = dir ? bih_b : bih_f;
  const float* __restrict__ bhh = dir ? bhh_b : bhh_f;
  const float* __restrict__ x2 = dir ? x2b : x2f;
  const int obase = dir ? 350 : 150;
  const int b0 = blk * 4;

  __shared__ __align__(16) float xh[2][104][4];

  const int oct = t >> 3;
  const int u   = (oct > 49) ? 49 : oct;
  const int l   = t & 7;
  const int cb  = 13 * l;           // 0..91
  float4 W0,W1,W2,W3,W4,W5,W6,W7,W8,W9,W10,W11,W12;
  #define L3LW(J, V) { const int g = cb + (J); \
    const float wr_ = (g<50) ? wih[(size_t)(u     )*50+g] : ((g<100)? whh[(size_t)(u     )*50+g-50] : 0.f); \
    const float wz_ = (g<50) ? wih[(size_t)(u + 50)*50+g] : ((g<100)? whh[(size_t)(u + 50)*50+g-50] : 0.f); \
    const float wx_ = (g<50) ? wih[(size_t)(u +100)*50+g] : 0.f; \
    const float wh_ = (g>=50 && g<100) ? whh[(size_t)(u +100)*50+g-50] : 0.f; \
    V = make_float4(wr_, wz_, wx_, wh_); }
  L3LW(0,W0) L3LW(1,W1) L3LW(2,W2) L3LW(3,W3) L3LW(4,W4) L3LW(5,W5) L3LW(6,W6)
  L3LW(7,W7) L3LW(8,W8) L3LW(9,W9) L3LW(10,W10) L3LW(11,W11) L3LW(12,W12)
  #undef L3LW
  const float bcr = bih[u] + bhh[u];
  const float bcz = bih[u+50] + bhh[u+50];
  const float bxn = bih[u+100];
  const float bhn = bhh[u+100];

  for (int i = t; i < 108; i += 512){            // zero h rows + pads, both buffers
    const int bi = (i >= 54) ? 1 : 0;
    const int row = 50 + (i - bi*54);
    *(float4*)&xh[bi][row][0] = make_float4(0.f,0.f,0.f,0.f);
  }
  if (t < 50)
    *(float4*)&xh[0][t][0] = *(const float4*)(x2 + (((size_t)0*256 + blk)*50 + t)*4);
  __syncthreads();

  #pragma unroll 1
  for (int s = 0; s < 32; ++s){
    const int cur = s & 1, nxt = cur ^ 1;
    if (t < 400){
      const float* hb = &xh[cur][cb][0];
      float ar0=0,ar1=0,ar2=0,ar3=0, az0=0,az1=0,az2=0,az3=0;
      float ax0=0,ax1=0,ax2=0,ax3=0, ah0=0,ah1=0,ah2=0,ah3=0;
      #define L3C(J, WV) { const float4 h4 = *(const float4*)(hb + 4*(J)); \
        ar0=fmaf(WV.x,h4.x,ar0); ar1=fmaf(WV.x,h4.y,ar1); ar2=fmaf(WV.x,h4.z,ar2); ar3=fmaf(WV.x,h4.w,ar3); \
        az0=fmaf(WV.y,h4.x,az0); az1=fmaf(WV.y,h4.y,az1); az2=fmaf(WV.y,h4.z,az2); az3=fmaf(WV.y,h4.w,az3); \
        ax0=fmaf(WV.z,h4.x,ax0); ax1=fmaf(WV.z,h4.y,ax1); ax2=fmaf(WV.z,h4.z,ax2); ax3=fmaf(WV.z,h4.w,ax3); \
        ah0=fmaf(WV.w,h4.x,ah0); ah1=fmaf(WV.w,h4.y,ah1); ah2=fmaf(WV.w,h4.z,ah2); ah3=fmaf(WV.w,h4.w,ah3); }
      L3C(0,W0) L3C(1,W1) L3C(2,W2) L3C(3,W3) L3C(4,W4) L3C(5,W5) L3C(6,W6)
      L3C(7,W7) L3C(8,W8) L3C(9,W9) L3C(10,W10) L3C(11,W11) L3C(12,W12)
      #undef L3C
      ar0=qsum(ar0); ar1=qsum(ar1); ar2=qsum(ar2); ar3=qsum(ar3);
      az0=qsum(az0); az1=qsum(az1); az2=qsum(az2); az3=qsum(az3);
      ax0=qsum(ax0); ax1=qsum(ax1); ax2=qsum(ax2); ax3=qsum(ax3);
      ah0=qsum(ah0); ah1=qsum(ah1); ah2=qsum(ah2); ah3=qsum(ah3);
      ar0=rsum4(ar0); ar1=rsum4(ar1); ar2=rsum4(ar2); ar3=rsum4(ar3);
      az0=rsum4(az0); az1=rsum4(az1); az2=rsum4(az2); az3=rsum4(az3);
      ax0=rsum4(ax0); ax1=rsum4(ax1); ax2=rsum4(ax2); ax3=rsum4(ax3);
      ah0=rsum4(ah0); ah1=rsum4(ah1); ah2=rsum4(ah2); ah3=rsum4(ah3);
      if (l < 4){
        const float Ar = sel4(l, make_float4(ar0,ar1,ar2,ar3));
        const float Az = sel4(l, make_float4(az0,az1,az2,az3));
        const float Ax = sel4(l, make_float4(ax0,ax1,ax2,ax3));
        const float Ah = sel4(l, make_float4(ah0,ah1,ah2,ah3));
        const float ho = xh[cur][50+u][l];
        const float r = sigf(Ar + bcr);
        const float z = sigf(Az + bcz);
        const float n = tanhf_fast(Ax + bxn + r*(Ah + bhn));
        const float hnew = n + z*(ho - n);
        xh[nxt][50+u][l] = hnew;
        if (s == 31) out[(size_t)(b0 + l)*400 + obase + u] = hnew;
      }
    } else if (t < 450){
      if (s + 1 < 32){
        const int j = t - 400;
        *(float4*)&xh[nxt][j][0] = *(const float4*)(x2 + (((size_t)(s+1)*256 + blk)*50 + j)*4);
      }
    }
    __syncthreads();
  }
}

extern "C" void kernel_launch(void* const* d_in, const int* in_sizes, int n_in,
                              void* d_out, int out_size, void* d_ws, size_t ws_size,
                              hipStream_t stream)
{
  const float* data   = (const float*)d_in[0];
  const float* f1_wih = (const float*)d_in[1];
  const float* f1_whh = (const float*)d_in[2];
  const float* f1_bih = (const float*)d_in[3];
  const float* f1_bhh = (const float*)d_in[4];
  const float* f2_wih = (const float*)d_in[5];
  const float* f2_whh = (const float*)d_in[6];
  const float* f2_bih = (const float*)d_in[7];
  const float* f2_bhh = (const float*)d_in[8];
  const float* f3_wih = (const float*)d_in[9];
  const float* f3_whh = (const float*)d_in[10];
  const float* f3_bih = (const float*)d_in[11];
  const float* f3_bhh = (const float*)d_in[12];
  const float* b1_wih = (const float*)d_in[13];
  const float* b1_whh = (const float*)d_in[14];
  const float* b1_bih = (const float*)d_in[15];
  const float* b1_bhh = (const float*)d_in[16];
  const float* b2_wih = (const float*)d_in[17];
  const float* b2_whh = (const float*)d_in[18];
  const float* b2_bih = (const float*)d_in[19];
  const float* b2_bhh = (const float*)d_in[20];
  const float* b3_wih = (const float*)d_in[21];
  const float* b3_whh = (const float*)d_in[22];
  const float* b3_bih = (const float*)d_in[23];
  const float* b3_bhh = (const float*)d_in[24];
  float* out = (float*)d_out;

  const size_t X1N = (size_t)128 * 256 * 100 * 4;  // [cs][blk][unit][chain]
  const size_t X2N = (size_t)32 * 256 * 50 * 4;    // [k2][blk][unit][chain]
  if (ws_size < (2 * X1N + 2 * X2N) * sizeof(float)) return;
  float* wsf = (float*)d_ws;
  float* x1f = wsf;
  float* x1b = wsf + X1N;
  float* x2f = wsf + 2 * X1N;
  float* x2b = wsf + 2 * X1N + X2N;

  gru_l1<<<dim3(128), dim3(448), 0, stream>>>(
      data, f1_wih, f1_whh, f1_bih, f1_bhh,
      b1_wih, b1_whh, b1_bih, b1_bhh, x1f, x1b, out);
  gru_l2<<<dim3(128), dim3(256), 0, stream>>>(
      x1f, x1b, f2_wih, f2_whh, f2_bih, f2_bhh,
      b2_wih, b2_whh, b2_bih, b2_bhh, x2f, x2b, out);
  gru_l3<<<dim3(512), dim3(512), 0, stream>>>(
      x2f, x2b, f3_wih, f3_whh, f3_bih, f3_bhh,
      b3_wih, b3_whh, b3_bih, b3_bhh, out);
}